// Round 1
// baseline (1953.414 us; speedup 1.0000x reference)
//
#include <hip/hip_runtime.h>
#include <stdint.h>

typedef unsigned int u32;
typedef unsigned long long u64;

#define NCLS 5
#define KMX 5
#define DD 32
#define LBN 4
#define KIT 5
#define MAXA 2048
#define CKK 25
#define NBLKA 256
#define FTINY 1.17549435e-38f

struct RKeys {
  u32 ki[LBN][2];
  u32 kf[LBN][2];
  u32 k1000[2];
  u32 k2000[2];
  u32 k2001[2];
};

struct SelState {
  u32 prefix1, rank1, prefix21, rank2, pivot_sv, target, M, ncand;
};

// ---------------- threefry2x32 (bit-exact JAX) ----------------
__host__ __device__ inline void tf2x32(u32 k0, u32 k1, u32 x0, u32 x1, u32* o0, u32* o1) {
  u32 ks2 = k0 ^ k1 ^ 0x1BD11BDAu;
  u32 ks[3] = {k0, k1, ks2};
  x0 += k0; x1 += k1;
  const int rotA[4] = {13, 15, 26, 6};
  const int rotB[4] = {17, 29, 16, 24};
#pragma unroll
  for (int g = 0; g < 5; ++g) {
#pragma unroll
    for (int j = 0; j < 4; ++j) {
      int r = (g & 1) ? rotB[j] : rotA[j];
      x0 += x1;
      x1 = (x1 << r) | (x1 >> (32 - r));
      x1 ^= x0;
    }
    x0 += ks[(g + 1) % 3];
    x1 += ks[(g + 2) % 3] + (u32)(g + 1);
  }
  *o0 = x0; *o1 = x1;
}

// JAX gumbel element: array of total size 2*half, element idx.
__device__ inline float jax_gumbel(u32 k0, u32 k1, u32 half, u32 idx) {
  bool hi = (idx >= half);
  u32 c0 = hi ? (idx - half) : idx;
  u32 c1 = hi ? idx : (idx + half);
  u32 o0, o1;
  tf2x32(k0, k1, c0, c1, &o0, &o1);
  u32 bits = hi ? o1 : o0;
  u32 fb = (bits >> 9) | 0x3F800000u;
  float f = __uint_as_float(fb) - 1.0f;
  float u = (f == 0.0f) ? FTINY : f;
  return -logf(-logf(u));
}

__device__ inline u32 f2sort(float f) {
  u32 b = __float_as_uint(f);
  return (b & 0x80000000u) ? ~b : (b | 0x80000000u);
}

#define INS5(kk, a0, a1, a2, a3, a4) do { u64 _k = (kk); \
  if (_k > a4) { a4 = _k; u64 _t; \
    if (a4 > a3) { _t = a3; a3 = a4; a4 = _t; } \
    if (a3 > a2) { _t = a2; a2 = a3; a3 = _t; } \
    if (a2 > a1) { _t = a1; a1 = a2; a2 = _t; } \
    if (a1 > a0) { _t = a0; a0 = a1; a1 = _t; } } } while (0)

// ---------------- kernels ----------------

__global__ void k_invnorm(const float* __restrict__ feats, float* __restrict__ invn, int N, int Z3) {
  int n = blockIdx.x * blockDim.x + threadIdx.x;
  if (n >= N) return;
  int b = n / Z3, v = n - b * Z3;
  const float* fp = feats + (size_t)b * DD * Z3 + v;
  float s = 0.f;
#pragma unroll
  for (int d = 0; d < DD; ++d) { float x = fp[(size_t)d * Z3]; s += x * x; }
  invn[n] = 1.0f / sqrtf(s + 1e-12f);
}

__global__ void k_protos(const float* __restrict__ protos, float* __restrict__ protn, float* __restrict__ compact) {
  int t = threadIdx.x;
  if (t < CKK) {
    float s = 0.f;
    for (int d = 0; d < DD; ++d) { float x = protos[t * DD + d]; s += x * x; }
    float dn = sqrtf(s + 1e-12f);
    for (int d = 0; d < DD; ++d) protn[t * DD + d] = protos[t * DD + d] / dn;
  }
  __syncthreads();
  if (t == 0) {
    float tot = 0.f;
    for (int c = 1; c < NCLS; ++c) {
      float acc = 0.f;
      for (int d = 0; d < DD; ++d) {
        float m = 0.f;
        for (int k = 0; k < KMX; ++k) m += protn[(c * KMX + k) * DD + d];
        m /= (float)KMX;
        float v = 0.f;
        for (int k = 0; k < KMX; ++k) { float df = protn[(c * KMX + k) * DD + d] - m; v += df * df; }
        acc += v / (float)(KMX - 1);
      }
      tot += acc / (float)DD;
    }
    compact[0] = tot;
  }
}

// kind 0: init gumbel (key ki, total N); kind 1..5: fb row it=kind-1 (key kf, total 5N)
__global__ void k_top5A(const int* __restrict__ gt, const int* __restrict__ labeled,
                        RKeys RK, u64* __restrict__ outA, int N) {
  int kind = blockIdx.y;
  int i = blockIdx.z;
  int c = labeled[i];
  u32 k0 = (kind == 0) ? RK.ki[i][0] : RK.kf[i][0];
  u32 k1 = (kind == 0) ? RK.ki[i][1] : RK.kf[i][1];
  u32 half = (kind == 0) ? (u32)(N / 2) : (u32)(((u64)5 * (u64)N) / 2);
  u32 base = (kind == 0) ? 0u : (u32)((u64)(kind - 1) * (u64)N);
  u64 t0 = 0, t1 = 0, t2 = 0, t3 = 0, t4 = 0;
  int stride = gridDim.x * blockDim.x;
  for (int n = blockIdx.x * blockDim.x + threadIdx.x; n < N; n += stride) {
    if (gt[n] != c) continue;
    float g = jax_gumbel(k0, k1, half, base + (u32)n);
    u64 key = ((u64)f2sort(g) << 32) | (u32)(~(u32)n);
    INS5(key, t0, t1, t2, t3, t4);
  }
  __shared__ u64 buf[256 * 5];
  int tid = threadIdx.x;
  buf[tid * 5 + 0] = t0; buf[tid * 5 + 1] = t1; buf[tid * 5 + 2] = t2;
  buf[tid * 5 + 3] = t3; buf[tid * 5 + 4] = t4;
  __syncthreads();
  if (tid == 0) {
    u64 m0 = 0, m1 = 0, m2 = 0, m3 = 0, m4 = 0;
    int tot = blockDim.x * 5;
    for (int j = 0; j < tot; ++j) { u64 k = buf[j]; INS5(k, m0, m1, m2, m3, m4); }
    u64* o = outA + (((size_t)kind * LBN + i) * gridDim.x + blockIdx.x) * 5;
    o[0] = m0; o[1] = m1; o[2] = m2; o[3] = m3; o[4] = m4;
  }
}

__global__ void k_top5B(const u64* __restrict__ outA, u64* __restrict__ top5F, int nblk) {
  int kind = blockIdx.x;
  int i = blockIdx.y;
  const u64* src = outA + ((size_t)kind * LBN + i) * nblk * 5;
  u64 t0 = 0, t1 = 0, t2 = 0, t3 = 0, t4 = 0;
  int tot = nblk * 5;
  for (int j = threadIdx.x; j < tot; j += blockDim.x) { u64 k = src[j]; INS5(k, t0, t1, t2, t3, t4); }
  __shared__ u64 buf[256 * 5];
  int tid = threadIdx.x;
  buf[tid * 5 + 0] = t0; buf[tid * 5 + 1] = t1; buf[tid * 5 + 2] = t2;
  buf[tid * 5 + 3] = t3; buf[tid * 5 + 4] = t4;
  __syncthreads();
  if (tid == 0) {
    u64 m0 = 0, m1 = 0, m2 = 0, m3 = 0, m4 = 0;
    int tt = blockDim.x * 5;
    for (int j = 0; j < tt; ++j) { u64 k = buf[j]; INS5(k, m0, m1, m2, m3, m4); }
    u64* o = top5F + ((size_t)kind * LBN + i) * 5;
    o[0] = m0; o[1] = m1; o[2] = m2; o[3] = m3; o[4] = m4;
  }
}

__global__ void k_initcent(const float* __restrict__ feats, const float* __restrict__ invn,
                           const u64* __restrict__ top5F, float* __restrict__ cent, int N, int Z3) {
  int t = threadIdx.x;
  if (t >= LBN * KMX * DD) return;
  int d = t & 31;
  int k = (t >> 5) % KMX;
  int i = t / (KMX * DD);
  u32 n = ~(u32)(top5F[((size_t)0 * LBN + i) * 5 + k]);
  if (n >= (u32)N) n = 0;
  int b = n / Z3, v = n - b * Z3;
  cent[(i * KMX + k) * DD + d] = feats[((size_t)(b * DD + d)) * Z3 + v] * invn[n];
}

__global__ void k_assign(const float* __restrict__ feats, const float* __restrict__ invn,
                         const int* __restrict__ gt, const int* __restrict__ labeled,
                         const float* __restrict__ cent, float* __restrict__ sums,
                         float* __restrict__ kcnt, int N, int Z3) {
  __shared__ float sc[LBN * KMX * DD];
  __shared__ float ssum[LBN * KMX * DD];
  __shared__ float scn[LBN * KMX];
  __shared__ float scnt[LBN * KMX];
  int tid = threadIdx.x;
  for (int t = tid; t < LBN * KMX * DD; t += blockDim.x) { sc[t] = cent[t]; ssum[t] = 0.f; }
  for (int t = tid; t < LBN * KMX; t += blockDim.x) scnt[t] = 0.f;
  __syncthreads();
  for (int t = tid; t < LBN * KMX; t += blockDim.x) {
    float s = 0.f;
#pragma unroll
    for (int d = 0; d < DD; ++d) s += sc[t * DD + d] * sc[t * DD + d];
    scn[t] = s;
  }
  __syncthreads();
  int lbv[LBN];
#pragma unroll
  for (int i = 0; i < LBN; ++i) lbv[i] = labeled[i];
  int stride = gridDim.x * blockDim.x;
  for (int n = blockIdx.x * blockDim.x + tid; n < N; n += stride) {
    int g = gt[n];
    bool any = false;
#pragma unroll
    for (int i = 0; i < LBN; ++i) any = any || (g == lbv[i]);
    if (!any) continue;
    int b = n / Z3, v = n - b * Z3;
    const float* fp = feats + (size_t)b * DD * Z3 + v;
    float inv = invn[n];
    float x[DD]; float sa = 0.f;
#pragma unroll
    for (int d = 0; d < DD; ++d) { x[d] = fp[(size_t)d * Z3] * inv; sa += x[d] * x[d]; }
#pragma unroll
    for (int i = 0; i < LBN; ++i) {
      if (g != lbv[i]) continue;
      int bestk = 0; float bestd = 3.4e38f;
#pragma unroll
      for (int k = 0; k < KMX; ++k) {
        float dot = 0.f;
#pragma unroll
        for (int d = 0; d < DD; ++d) dot += x[d] * sc[(i * KMX + k) * DD + d];
        float d2 = (sa + scn[i * KMX + k]) - 2.0f * dot;
        float dd = sqrtf(fmaxf(d2, 0.f));
        if (dd < bestd) { bestd = dd; bestk = k; }
      }
      atomicAdd(&scnt[i * KMX + bestk], 1.0f);
      float* dst = &ssum[(i * KMX + bestk) * DD];
#pragma unroll
      for (int d = 0; d < DD; ++d) atomicAdd(&dst[d], x[d]);
    }
  }
  __syncthreads();
  for (int t = tid; t < LBN * KMX * DD; t += blockDim.x) if (ssum[t] != 0.f) atomicAdd(&sums[t], ssum[t]);
  for (int t = tid; t < LBN * KMX; t += blockDim.x) if (scnt[t] != 0.f) atomicAdd(&kcnt[t], scnt[t]);
}

__global__ void k_update(const float* __restrict__ feats, const float* __restrict__ invn,
                         const u64* __restrict__ top5F, const float* __restrict__ sums,
                         const float* __restrict__ kcnt, float* __restrict__ cent,
                         int iter, int N, int Z3) {
  int t = threadIdx.x;
  if (t >= LBN * KMX * DD) return;
  int d = t & 31;
  int k = (t >> 5) % KMX;
  int i = t / (KMX * DD);
  int ik = i * KMX + k;
  float c = kcnt[ik];
  float val;
  if (c > 0.f) {
    val = sums[ik * DD + d] / fmaxf(c, 1.0f);
  } else {
    u32 n = ~(u32)(top5F[((size_t)(1 + iter) * LBN + i) * 5 + k]);
    if (n >= (u32)N) n = 0;
    int b = n / Z3, v = n - b * Z3;
    val = feats[((size_t)(b * DD + d)) * Z3 + v] * invn[n];
  }
  cent[ik * DD + d] = val;
}

__global__ void k_anchor_final(const float* __restrict__ cent, const float* __restrict__ sums,
                               const float* __restrict__ kcnt, const float* __restrict__ protn,
                               const int* __restrict__ labeled, float* __restrict__ accum) {
  if (threadIdx.x != 0) return;
  int i = blockIdx.x;
  int c = labeled[i];
  float cnt = 0.f;
  float meanv[DD];
  for (int d = 0; d < DD; ++d) meanv[d] = 0.f;
  for (int k = 0; k < KMX; ++k) {
    cnt += kcnt[i * KMX + k];
    for (int d = 0; d < DD; ++d) meanv[d] += sums[(i * KMX + k) * DD + d];
  }
  for (int d = 0; d < DD; ++d) meanv[d] /= fmaxf(cnt, 1.0f);
  int cs = c < 0 ? 0 : (c > NCLS - 1 ? NCLS - 1 : c);
  float ls = 0.f;
  if (cnt >= (float)KMX) {
    // kmeans branch: normalize twice
    for (int k = 0; k < KMX; ++k) {
      float v[DD]; float s = 0.f;
      for (int d = 0; d < DD; ++d) { v[d] = cent[(i * KMX + k) * DD + d]; s += v[d] * v[d]; }
      float dn1 = sqrtf(s + 1e-12f);
      float s2 = 0.f;
      for (int d = 0; d < DD; ++d) { v[d] = v[d] / dn1; s2 += v[d] * v[d]; }
      float dn2 = sqrtf(s2 + 1e-12f);
      for (int d = 0; d < DD; ++d) {
        float vv = v[d] / dn2;
        float df = protn[(cs * KMX + k) * DD + d] - vv;
        ls += df * df;
      }
    }
  } else {
    // mean_rep branch: normalize once
    float s = 0.f;
    for (int d = 0; d < DD; ++d) s += meanv[d] * meanv[d];
    float dn = sqrtf(s + 1e-12f);
    for (int k = 0; k < KMX; ++k)
      for (int d = 0; d < DD; ++d) {
        float vv = meanv[d] / dn;
        float df = protn[(cs * KMX + k) * DD + d] - vv;
        ls += df * df;
      }
  }
  ls /= (float)(KMX * DD);
  bool valid = (c != 0) && (c < NCLS) && (cnt > 0.f);
  if (valid) { atomicAdd(&accum[0], ls); atomicAdd(&accum[1], 1.0f); }
}

__global__ void k_hist(const int* __restrict__ pseudo, RKeys RK, u32* __restrict__ hist,
                       const SelState* __restrict__ st, int pass, int N) {
  __shared__ u32 h[2048];
  for (int t = threadIdx.x; t < 2048; t += blockDim.x) h[t] = 0;
  __syncthreads();
  u32 half = (u32)(N / 2);
  u32 pre1 = 0, pre21 = 0;
  if (pass >= 1) pre1 = st->prefix1;
  if (pass == 2) pre21 = st->prefix21;
  int stride = gridDim.x * blockDim.x;
  for (int n = blockIdx.x * blockDim.x + threadIdx.x; n < N; n += stride) {
    if (pseudo[n] <= 0) continue;
    float g = jax_gumbel(RK.k1000[0], RK.k1000[1], half, (u32)n);
    u32 sv = f2sort(g);
    int bin = -1;
    if (pass == 0) bin = (int)(sv >> 21);
    else if (pass == 1) { if ((sv >> 21) == pre1) bin = (int)((sv >> 10) & 0x7FFu); }
    else { if ((sv >> 10) == pre21) bin = (int)(sv & 0x3FFu); }
    if (bin >= 0) atomicAdd(&h[bin], 1u);
  }
  __syncthreads();
  for (int t = threadIdx.x; t < 2048; t += blockDim.x) if (h[t]) atomicAdd(&hist[t], h[t]);
}

__global__ void k_scan(const u32* __restrict__ hist, SelState* st, int pass) {
  if (threadIdx.x != 0 || blockIdx.x != 0) return;
  if (pass == 0) {
    u64 tot = 0;
    for (int b = 0; b < 2048; ++b) tot += hist[b];
    st->M = (u32)tot;
    st->target = (u32)(tot < (u64)MAXA ? tot : (u64)MAXA);
  }
  u32 rank = (pass == 0) ? st->target : (pass == 1 ? st->rank1 : st->rank2);
  int nb = (pass == 2) ? 1024 : 2048;
  u64 cum = 0; int found = -1; u32 rem = 0;
  if (rank > 0) {
    for (int b = nb - 1; b >= 0; --b) {
      u32 c = hist[b];
      if (cum < (u64)rank && (u64)rank <= cum + c) { found = b; rem = rank - (u32)cum; break; }
      cum += c;
    }
  }
  if (pass == 0) {
    if (found < 0) { st->prefix1 = 0xFFFFFFFFu; st->rank1 = 0; }
    else { st->prefix1 = (u32)found; st->rank1 = rem; }
  } else if (pass == 1) {
    if (found < 0) { st->prefix21 = 0xFFFFFFFFu; st->rank2 = 0; }
    else { st->prefix21 = (st->prefix1 << 11) | (u32)found; st->rank2 = rem; }
  } else {
    if (found < 0) st->pivot_sv = 0xFFFFFFFFu;
    else st->pivot_sv = (st->prefix21 << 10) | (u32)found;
  }
}

__global__ void k_gather(const int* __restrict__ pseudo, RKeys RK, SelState* st,
                         u64* __restrict__ cand, int N) {
  if (st->target == 0) return;
  u32 piv = st->pivot_sv;
  u32 half = (u32)(N / 2);
  int stride = gridDim.x * blockDim.x;
  for (int n = blockIdx.x * blockDim.x + threadIdx.x; n < N; n += stride) {
    if (pseudo[n] <= 0) continue;
    float g = jax_gumbel(RK.k1000[0], RK.k1000[1], half, (u32)n);
    u32 sv = f2sort(g);
    if (sv >= piv) {
      u32 p = atomicAdd(&st->ncand, 1u);
      if (p < 4096u) cand[p] = ((u64)sv << 32) | (u32)(~(u32)n);
    }
  }
}

__global__ void __launch_bounds__(1024) k_sortsel(const u64* __restrict__ cand,
                                                  const SelState* __restrict__ st,
                                                  int* __restrict__ aidx) {
  __shared__ u64 s[4096];
  u32 nc = st->ncand; if (nc > 4096u) nc = 4096u;
  u32 target = st->target;
  for (int t = threadIdx.x; t < 4096; t += blockDim.x) s[t] = (t < (int)nc) ? cand[t] : 0ULL;
  __syncthreads();
  for (u32 ksz = 2; ksz <= 4096; ksz <<= 1) {
    for (u32 j = ksz >> 1; j > 0; j >>= 1) {
      for (u32 idx = threadIdx.x; idx < 4096; idx += blockDim.x) {
        u32 ixj = idx ^ j;
        if (ixj > idx) {
          bool up = (idx & ksz) == 0;
          u64 A = s[idx], B = s[ixj];
          bool sw = up ? (A < B) : (A > B);  // descending final order
          if (sw) { s[idx] = B; s[ixj] = A; }
        }
      }
      __syncthreads();
    }
  }
  for (int t = threadIdx.x; t < MAXA; t += blockDim.x)
    if (t < (int)target) aidx[t] = (int)(~(u32)s[t]);
}

__global__ void k_prep(const float* __restrict__ feats, const float* __restrict__ invn,
                       const int* __restrict__ pseudo, const SelState* __restrict__ st,
                       const int* __restrict__ aidx, float* __restrict__ afe,
                       int* __restrict__ alab, int N, int Z3) {
  int r = blockIdx.x * blockDim.x + threadIdx.x;
  if (r >= (int)st->target) return;
  int n = aidx[r];
  if ((u32)n >= (u32)N) n = 0;
  int lb = pseudo[n];
  lb = lb < 0 ? 0 : (lb > NCLS - 1 ? NCLS - 1 : lb);
  alab[r] = lb;
  int b = n / Z3, v = n - b * Z3;
  float inv = invn[n];
#pragma unroll
  for (int d = 0; d < DD; ++d)
    afe[(size_t)r * DD + d] = feats[((size_t)(b * DD + d)) * Z3 + v] * inv;
}

__global__ void k_triplet(const float* __restrict__ protn, const float* __restrict__ afe,
                          const int* __restrict__ alab, const SelState* __restrict__ st,
                          RKeys RK, float* __restrict__ acc) {
  __shared__ float pn[CKK * DD];
  __shared__ float spn[CKK];
  int tid = threadIdx.x;
  for (int t = tid; t < CKK * DD; t += blockDim.x) pn[t] = protn[t];
  __syncthreads();
  if (tid < CKK) {
    float s = 0.f;
    for (int d = 0; d < DD; ++d) s += pn[tid * DD + d] * pn[tid * DD + d];
    spn[tid] = s;
  }
  __syncthreads();
  int r = blockIdx.x * blockDim.x + tid;
  if (r >= (int)st->target) return;
  float a[DD]; float sa = 0.f;
#pragma unroll
  for (int d = 0; d < DD; ++d) { a[d] = afe[(size_t)r * DD + d]; sa += a[d] * a[d]; }
  int lab = alab[r];
  int ob = lab * KMX;
  // pos_idx: argmax sim over own columns (first-max); pos_d: min dist over own
  float bs = -3.4e38f; int pidx = ob;
  float pos_d = 3.4e38f;
  for (int k = ob; k < ob + KMX; ++k) {
    float dot = 0.f;
#pragma unroll
    for (int d = 0; d < DD; ++d) dot += a[d] * pn[k * DD + d];
    if (dot > bs) { bs = dot; pidx = k; }
    float d2 = (sa + spn[k]) - 2.0f * dot;
    float dd = sqrtf(fmaxf(d2, 0.f));
    pos_d = fminf(pos_d, dd);
  }
  // negatives: semi-hard via g1, else random via g2
  u32 halfT = (u32)(MAXA * CKK / 2);
  bool any_semi = false;
  float bg1 = -3.4e38f; int k1i = 0;
  float bg2 = -3.4e38f; int k2i = 0;
  for (int k = 0; k < CKK; ++k) {
    if (k / KMX == lab) continue;  // own class: not a negative
    float dot = 0.f;
#pragma unroll
    for (int d = 0; d < DD; ++d) dot += a[d] * pn[k * DD + d];
    float d2 = (sa + spn[k]) - 2.0f * dot;
    float dd = sqrtf(fmaxf(d2, 0.f));
    u32 j = (u32)(r * CKK + k);
    bool semi = (dd > pos_d) && (dd < pos_d + 1.0f);
    if (semi) {
      float g1 = jax_gumbel(RK.k2000[0], RK.k2000[1], halfT, j);
      any_semi = true;
      if (g1 > bg1) { bg1 = g1; k1i = k; }
    }
    float g2 = jax_gumbel(RK.k2001[0], RK.k2001[1], halfT, j);
    if (g2 > bg2) { bg2 = g2; k2i = k; }
  }
  int nidx = any_semi ? k1i : k2i;
  // normalized triplet distances
  float aden = sqrtf(sa + 1e-12f);
  float pden = sqrtf(spn[pidx] + 1e-12f);
  float nden = sqrtf(spn[nidx] + 1e-12f);
  float s1 = 0.f, s2 = 0.f;
#pragma unroll
  for (int d = 0; d < DD; ++d) {
    float an = a[d] / aden;
    float pv = pn[pidx * DD + d] / pden;
    float nv = pn[nidx * DD + d] / nden;
    float t1 = an - pv; s1 += t1 * t1;
    float t2 = an - nv; s2 += t2 * t2;
  }
  float d_pos = sqrtf(s1 + 1e-12f);
  float d_neg = sqrtf(s2 + 1e-12f);
  float xx = (d_pos - d_neg) + 1.0f;
  float l = fmaxf(xx, 0.f) + log1pf(expf(-fabsf(xx)));
  atomicAdd(&acc[0], l);
  atomicAdd(&acc[1], 1.0f);
}

__global__ void k_final(const float* __restrict__ anchor_acc, const float* __restrict__ proto_acc,
                        const float* __restrict__ compact, float* __restrict__ out) {
  if (threadIdx.x != 0 || blockIdx.x != 0) return;
  float al = anchor_acc[0] / fmaxf(anchor_acc[1], 1.0f);
  float pl = proto_acc[0] / fmaxf(proto_acc[1], 1.0f);
  out[0] = pl + 1.0f * al + 0.1f * compact[0];
}

// ---------------- host ----------------

static void host_keys(RKeys* K) {
  const u32 b0 = 0u, b1 = 42u;  // jax.random.key(42) -> [0, 42]
  u32 o0, o1;
  for (int i = 0; i < LBN; ++i) {
    u32 f0, f1;
    tf2x32(b0, b1, 0u, (u32)i, &f0, &f1);          // fold_in(key, i)
    u32 p0, q0, p1, q1;
    tf2x32(f0, f1, 0u, 2u, &p0, &q0);              // split: lane 0 -> counts (0,2)
    tf2x32(f0, f1, 1u, 3u, &p1, &q1);              // split: lane 1 -> counts (1,3)
    K->ki[i][0] = p0; K->ki[i][1] = p1;            // k_init = (y0_lane0, y0_lane1)
    K->kf[i][0] = q0; K->kf[i][1] = q1;            // k_fb   = (y1_lane0, y1_lane1)
  }
  tf2x32(b0, b1, 0u, 1000u, &o0, &o1); K->k1000[0] = o0; K->k1000[1] = o1;
  tf2x32(b0, b1, 0u, 2000u, &o0, &o1); K->k2000[0] = o0; K->k2000[1] = o1;
  tf2x32(b0, b1, 0u, 2001u, &o0, &o1); K->k2001[0] = o0; K->k2001[1] = o1;
}

extern "C" void kernel_launch(void* const* d_in, const int* in_sizes, int n_in,
                              void* d_out, int out_size, void* d_ws, size_t ws_size,
                              hipStream_t stream) {
  const float* feats = (const float*)d_in[0];
  const float* protos = (const float*)d_in[1];
  const int* pseudo = (const int*)d_in[2];
  const int* gt = (const int*)d_in[3];
  const int* labeled = (const int*)d_in[4];
  float* out = (float*)d_out;

  int N = in_sizes[2];
  int Z3 = N / 4;  // B = 4 per setup_inputs

  RKeys RK;
  host_keys(&RK);

  // workspace layout (256B aligned chunks)
  char* W = (char*)d_ws;
  size_t off = 0;
  auto alloc = [&](size_t bytes) -> char* {
    char* p = W + off;
    off += (bytes + 255) & ~(size_t)255;
    return p;
  };
  float* invn = (float*)alloc((size_t)N * 4);
  char* stateBase = W + off;
  u64* top5A = (u64*)alloc((size_t)6 * LBN * NBLKA * 5 * 8);
  u64* top5F = (u64*)alloc((size_t)6 * LBN * 5 * 8);
  float* cent = (float*)alloc((size_t)LBN * KMX * DD * 4);
  float* sums = (float*)alloc((size_t)(LBN * KMX * DD + LBN * KMX) * 4);  // sums + kcnt contiguous
  float* kcnt = sums + LBN * KMX * DD;
  float* protn = (float*)alloc((size_t)CKK * DD * 4);
  float* compact = (float*)alloc(256);
  float* anchor_acc = (float*)alloc(256);
  float* proto_acc = (float*)alloc(256);
  u32* hist = (u32*)alloc(2048 * 4);
  SelState* st = (SelState*)alloc(256);
  u64* cand = (u64*)alloc(4096 * 8);
  int* aidx = (int*)alloc((size_t)MAXA * 4);
  int* alab = (int*)alloc((size_t)MAXA * 4);
  float* afe = (float*)alloc((size_t)MAXA * DD * 4);
  if (ws_size < off) return;  // insufficient workspace; bail cleanly

  size_t stateBytes = (size_t)((W + off) - stateBase);
  hipMemsetAsync(stateBase, 0, stateBytes, stream);

  // 1. per-voxel inverse norms
  k_invnorm<<<dim3((N + 255) / 256), dim3(256), 0, stream>>>(feats, invn, N, Z3);

  // 2. normalized prototypes + compactness
  k_protos<<<dim3(1), dim3(64), 0, stream>>>(protos, protn, compact);

  // 3. top-5 gumbel selections (init + 5 fallback rows, all 4 labeled classes)
  k_top5A<<<dim3(NBLKA, 6, LBN), dim3(256), 0, stream>>>(gt, labeled, RK, top5A, N);
  k_top5B<<<dim3(6, LBN), dim3(256), 0, stream>>>(top5A, top5F, NBLKA);

  // 4. kmeans
  k_initcent<<<dim3(1), dim3(LBN * KMX * DD), 0, stream>>>(feats, invn, top5F, cent, N, Z3);
  for (int it = 0; it < KIT; ++it) {
    hipMemsetAsync(sums, 0, (size_t)(LBN * KMX * DD + LBN * KMX) * 4, stream);
    k_assign<<<dim3(512), dim3(256), 0, stream>>>(feats, invn, gt, labeled, cent, sums, kcnt, N, Z3);
    k_update<<<dim3(1), dim3(LBN * KMX * DD), 0, stream>>>(feats, invn, top5F, sums, kcnt, cent, it, N, Z3);
  }
  k_anchor_final<<<dim3(LBN), dim3(64), 0, stream>>>(cent, sums, kcnt, protn, labeled, anchor_acc);

  // 5. anchor selection: exact top-2048 gumbel via 3-pass radix threshold + sort
  k_hist<<<dim3(1024), dim3(256), 0, stream>>>(pseudo, RK, hist, st, 0, N);
  k_scan<<<dim3(1), dim3(64), 0, stream>>>(hist, st, 0);
  hipMemsetAsync(hist, 0, 2048 * 4, stream);
  k_hist<<<dim3(1024), dim3(256), 0, stream>>>(pseudo, RK, hist, st, 1, N);
  k_scan<<<dim3(1), dim3(64), 0, stream>>>(hist, st, 1);
  hipMemsetAsync(hist, 0, 2048 * 4, stream);
  k_hist<<<dim3(1024), dim3(256), 0, stream>>>(pseudo, RK, hist, st, 2, N);
  k_scan<<<dim3(1), dim3(64), 0, stream>>>(hist, st, 2);
  k_gather<<<dim3(1024), dim3(256), 0, stream>>>(pseudo, RK, st, cand, N);
  k_sortsel<<<dim3(1), dim3(1024), 0, stream>>>(cand, st, aidx);

  // 6. triplet loss
  k_prep<<<dim3(MAXA / 256), dim3(256), 0, stream>>>(feats, invn, pseudo, st, aidx, afe, alab, N, Z3);
  k_triplet<<<dim3(MAXA / 256), dim3(256), 0, stream>>>(protn, afe, alab, st, RK, proto_acc);

  // 7. combine
  k_final<<<dim3(1), dim3(64), 0, stream>>>(anchor_acc, proto_acc, compact, out);
}

// Round 2
// 1376.951 us; speedup vs baseline: 1.4187x; 1.4187x over previous
//
#include <hip/hip_runtime.h>
#include <stdint.h>

typedef unsigned int u32;
typedef unsigned long long u64;

#define NCLS 5
#define KMX 5
#define DD 32
#define LBN 4
#define KIT 5
#define MAXA 2048
#define CKK 25
#define NBLKA 64
#define FTINY 1.17549435e-38f

struct RKeys {
  u32 ki[LBN][2];
  u32 kf[LBN][2];
  u32 k1000[2];
  u32 k2000[2];
  u32 k2001[2];
};

struct SelState {
  u32 prefix1, rank1, prefix21, rank2, pivot_sv, target, M, ncand;
};

// ---------------- threefry2x32 (bit-exact JAX) ----------------
__host__ __device__ inline void tf2x32(u32 k0, u32 k1, u32 x0, u32 x1, u32* o0, u32* o1) {
  u32 ks2 = k0 ^ k1 ^ 0x1BD11BDAu;
  u32 ks[3] = {k0, k1, ks2};
  x0 += k0; x1 += k1;
  const int rotA[4] = {13, 15, 26, 6};
  const int rotB[4] = {17, 29, 16, 24};
#pragma unroll
  for (int g = 0; g < 5; ++g) {
#pragma unroll
    for (int j = 0; j < 4; ++j) {
      int r = (g & 1) ? rotB[j] : rotA[j];
      x0 += x1;
      x1 = (x1 << r) | (x1 >> (32 - r));
      x1 ^= x0;
    }
    x0 += ks[(g + 1) % 3];
    x1 += ks[(g + 2) % 3] + (u32)(g + 1);
  }
  *o0 = x0; *o1 = x1;
}

__device__ inline float jax_gumbel(u32 k0, u32 k1, u32 half, u32 idx) {
  bool hi = (idx >= half);
  u32 c0 = hi ? (idx - half) : idx;
  u32 c1 = hi ? idx : (idx + half);
  u32 o0, o1;
  tf2x32(k0, k1, c0, c1, &o0, &o1);
  u32 bits = hi ? o1 : o0;
  u32 fb = (bits >> 9) | 0x3F800000u;
  float f = __uint_as_float(fb) - 1.0f;
  float u = (f == 0.0f) ? FTINY : f;
  return -logf(-logf(u));
}

__device__ inline u32 f2sort(float f) {
  u32 b = __float_as_uint(f);
  return (b & 0x80000000u) ? ~b : (b | 0x80000000u);
}

#define INS5(kk, a0, a1, a2, a3, a4) do { u64 _k = (kk); \
  if (_k > a4) { a4 = _k; u64 _t; \
    if (a4 > a3) { _t = a3; a3 = a4; a4 = _t; } \
    if (a3 > a2) { _t = a2; a2 = a3; a3 = _t; } \
    if (a2 > a1) { _t = a1; a1 = a2; a2 = _t; } \
    if (a1 > a0) { _t = a0; a0 = a1; a1 = _t; } } } while (0)

#define WMERGE(off) do { \
  u64 r0 = __shfl_xor(t0, off, 64), r1 = __shfl_xor(t1, off, 64), \
      r2 = __shfl_xor(t2, off, 64), r3 = __shfl_xor(t3, off, 64), \
      r4 = __shfl_xor(t4, off, 64); \
  INS5(r0, t0, t1, t2, t3, t4); INS5(r1, t0, t1, t2, t3, t4); \
  INS5(r2, t0, t1, t2, t3, t4); INS5(r3, t0, t1, t2, t3, t4); \
  INS5(r4, t0, t1, t2, t3, t4); } while (0)

__device__ inline float rsum32(float v) {
#pragma unroll
  for (int o = 16; o; o >>= 1) v += __shfl_xor(v, o, 32);
  return v;
}

// ---------------- kernels ----------------

__global__ void k_invnorm(const float* __restrict__ feats, float* __restrict__ invn, int N, int Z3) {
  int n = blockIdx.x * blockDim.x + threadIdx.x;
  if (n >= N) return;
  int b = n / Z3, v = n - b * Z3;
  const float* fp = feats + (size_t)b * DD * Z3 + v;
  float s = 0.f;
#pragma unroll
  for (int d = 0; d < DD; ++d) { float x = fp[(size_t)d * Z3]; s += x * x; }
  invn[n] = 1.0f / sqrtf(s + 1e-12f);
}

__global__ void k_protos(const float* __restrict__ protos, float* __restrict__ protn, float* __restrict__ compact) {
  __shared__ float pl[CKK * DD];
  __shared__ float rn[CKK];
  __shared__ float red[4];
  int tid = threadIdx.x;  // 256
  for (int t = tid; t < CKK * DD; t += 256) pl[t] = protos[t];
  __syncthreads();
  if (tid < CKK) {
    float s = 0.f;
    for (int d = 0; d < DD; ++d) { float x = pl[tid * DD + d]; s += x * x; }
    rn[tid] = sqrtf(s + 1e-12f);
  }
  __syncthreads();
  for (int t = tid; t < CKK * DD; t += 256) {
    float v = pl[t] / rn[t / DD];
    pl[t] = v;
    protn[t] = v;
  }
  __syncthreads();
  // compactness: per (c,d) unbiased variance over K
  float part = 0.f;
  if (tid < (NCLS - 1) * DD) {
    int c = 1 + tid / DD;
    int d = tid % DD;
    float m = 0.f;
#pragma unroll
    for (int k = 0; k < KMX; ++k) m += pl[(c * KMX + k) * DD + d];
    m *= (1.0f / KMX);
    float v = 0.f;
#pragma unroll
    for (int k = 0; k < KMX; ++k) { float df = pl[(c * KMX + k) * DD + d] - m; v += df * df; }
    part = v * (1.0f / (KMX - 1)) * (1.0f / DD);
  }
#pragma unroll
  for (int o = 32; o; o >>= 1) part += __shfl_xor(part, o, 64);
  int wid = tid >> 6;
  if ((tid & 63) == 0) red[wid] = part;
  __syncthreads();
  if (tid == 0) compact[0] = red[0] + red[1] + red[2] + red[3];
}

// kind 0: init gumbel (key ki, total N); kind 1..5: fb row it=kind-1 (key kf, total 5N)
__global__ void k_top5A(const int* __restrict__ gt, const int* __restrict__ labeled,
                        RKeys RK, u64* __restrict__ outA, int N) {
  int kind = blockIdx.y;
  int i = blockIdx.z;
  int c = labeled[i];
  u32 k0 = (kind == 0) ? RK.ki[i][0] : RK.kf[i][0];
  u32 k1 = (kind == 0) ? RK.ki[i][1] : RK.kf[i][1];
  u32 half = (kind == 0) ? (u32)(N / 2) : (u32)(((u64)5 * (u64)N) / 2);
  u32 base = (kind == 0) ? 0u : (u32)((u64)(kind - 1) * (u64)N);
  u64 t0 = 0, t1 = 0, t2 = 0, t3 = 0, t4 = 0;
  int stride = gridDim.x * blockDim.x;
  for (int n = blockIdx.x * blockDim.x + threadIdx.x; n < N; n += stride) {
    if (gt[n] != c) continue;
    float g = jax_gumbel(k0, k1, half, base + (u32)n);
    u64 key = ((u64)f2sort(g) << 32) | (u32)(~(u32)n);
    INS5(key, t0, t1, t2, t3, t4);
  }
  // wave butterfly merge
  WMERGE(32); WMERGE(16); WMERGE(8); WMERGE(4); WMERGE(2); WMERGE(1);
  __shared__ u64 wbuf[4 * 5];
  int tid = threadIdx.x;
  int wid = tid >> 6;
  if ((tid & 63) == 0) {
    wbuf[wid * 5 + 0] = t0; wbuf[wid * 5 + 1] = t1; wbuf[wid * 5 + 2] = t2;
    wbuf[wid * 5 + 3] = t3; wbuf[wid * 5 + 4] = t4;
  }
  __syncthreads();
  if (tid == 0) {
#pragma unroll
    for (int w = 1; w < 4; ++w)
#pragma unroll
      for (int j = 0; j < 5; ++j) { u64 k = wbuf[w * 5 + j]; INS5(k, t0, t1, t2, t3, t4); }
    u64* o = outA + (((size_t)kind * LBN + i) * gridDim.x + blockIdx.x) * 5;
    o[0] = t0; o[1] = t1; o[2] = t2; o[3] = t3; o[4] = t4;
  }
}

__global__ void k_top5B(const u64* __restrict__ outA, u64* __restrict__ top5F, int nblk) {
  int kind = blockIdx.x;
  int i = blockIdx.y;
  const u64* src = outA + ((size_t)kind * LBN + i) * nblk * 5;
  u64 t0 = 0, t1 = 0, t2 = 0, t3 = 0, t4 = 0;
  int tot = nblk * 5;
  for (int j = threadIdx.x; j < tot; j += blockDim.x) { u64 k = src[j]; INS5(k, t0, t1, t2, t3, t4); }
  WMERGE(32); WMERGE(16); WMERGE(8); WMERGE(4); WMERGE(2); WMERGE(1);
  __shared__ u64 wbuf[4 * 5];
  int tid = threadIdx.x;
  int wid = tid >> 6;
  if ((tid & 63) == 0) {
    wbuf[wid * 5 + 0] = t0; wbuf[wid * 5 + 1] = t1; wbuf[wid * 5 + 2] = t2;
    wbuf[wid * 5 + 3] = t3; wbuf[wid * 5 + 4] = t4;
  }
  __syncthreads();
  if (tid == 0) {
#pragma unroll
    for (int w = 1; w < 4; ++w)
#pragma unroll
      for (int j = 0; j < 5; ++j) { u64 k = wbuf[w * 5 + j]; INS5(k, t0, t1, t2, t3, t4); }
    u64* o = top5F + ((size_t)kind * LBN + i) * 5;
    o[0] = t0; o[1] = t1; o[2] = t2; o[3] = t3; o[4] = t4;
  }
}

__global__ void k_initcent(const float* __restrict__ feats, const float* __restrict__ invn,
                           const u64* __restrict__ top5F, float* __restrict__ cent, int N, int Z3) {
  int t = threadIdx.x;
  if (t >= LBN * KMX * DD) return;
  int d = t & 31;
  int k = (t >> 5) % KMX;
  int i = t / (KMX * DD);
  u32 n = ~(u32)(top5F[((size_t)0 * LBN + i) * 5 + k]);
  if (n >= (u32)N) n = 0;
  int b = n / Z3, v = n - b * Z3;
  cent[(i * KMX + k) * DD + d] = feats[((size_t)(b * DD + d)) * Z3 + v] * invn[n];
}

__global__ void k_assign(const float* __restrict__ feats, const float* __restrict__ invn,
                         const int* __restrict__ gt, const int* __restrict__ labeled,
                         const float* __restrict__ cent, float* __restrict__ sums,
                         float* __restrict__ kcnt, int N, int Z3) {
  __shared__ float sc[LBN * KMX * DD];
  __shared__ float ssum[LBN * KMX * 33];  // cluster stride 33: distinct banks per cluster
  __shared__ float scn[LBN * KMX];
  __shared__ float scnt[LBN * KMX];
  int tid = threadIdx.x;
  for (int t = tid; t < LBN * KMX * DD; t += blockDim.x) sc[t] = cent[t];
  for (int t = tid; t < LBN * KMX * 33; t += blockDim.x) ssum[t] = 0.f;
  for (int t = tid; t < LBN * KMX; t += blockDim.x) scnt[t] = 0.f;
  __syncthreads();
  for (int t = tid; t < LBN * KMX; t += blockDim.x) {
    float s = 0.f;
#pragma unroll
    for (int d = 0; d < DD; ++d) s += sc[t * DD + d] * sc[t * DD + d];
    scn[t] = s;
  }
  __syncthreads();
  int lbv[LBN];
#pragma unroll
  for (int i = 0; i < LBN; ++i) lbv[i] = labeled[i];
  int stride = gridDim.x * blockDim.x;
  for (int n = blockIdx.x * blockDim.x + tid; n < N; n += stride) {
    int g = gt[n];
    bool any = false;
#pragma unroll
    for (int i = 0; i < LBN; ++i) any = any || (g == lbv[i]);
    if (!any) continue;
    int b = n / Z3, v = n - b * Z3;
    const float* fp = feats + (size_t)b * DD * Z3 + v;
    float inv = invn[n];
    float x[DD]; float sa = 0.f;
#pragma unroll
    for (int d = 0; d < DD; ++d) { x[d] = fp[(size_t)d * Z3] * inv; sa += x[d] * x[d]; }
#pragma unroll
    for (int i = 0; i < LBN; ++i) {
      if (g != lbv[i]) continue;
      int bestk = 0; float bestd = 3.4e38f;
#pragma unroll
      for (int k = 0; k < KMX; ++k) {
        float dot = 0.f;
#pragma unroll
        for (int d = 0; d < DD; ++d) dot += x[d] * sc[(i * KMX + k) * DD + d];
        float d2 = (sa + scn[i * KMX + k]) - 2.0f * dot;  // argmin(sqrt) == argmin(d2)
        if (d2 < bestd) { bestd = d2; bestk = k; }
      }
      atomicAdd(&scnt[i * KMX + bestk], 1.0f);
      float* dst = &ssum[(i * KMX + bestk) * 33];
#pragma unroll
      for (int d = 0; d < DD; ++d) atomicAdd(&dst[d], x[d]);
    }
  }
  __syncthreads();
  for (int t = tid; t < LBN * KMX * DD; t += blockDim.x) {
    int cl = t / DD, d = t - cl * DD;
    float v = ssum[cl * 33 + d];
    if (v != 0.f) atomicAdd(&sums[t], v);
  }
  for (int t = tid; t < LBN * KMX; t += blockDim.x) if (scnt[t] != 0.f) atomicAdd(&kcnt[t], scnt[t]);
}

__global__ void k_update(const float* __restrict__ feats, const float* __restrict__ invn,
                         const u64* __restrict__ top5F, const float* __restrict__ sums,
                         const float* __restrict__ kcnt, float* __restrict__ cent,
                         int iter, int N, int Z3) {
  int t = threadIdx.x;
  if (t >= LBN * KMX * DD) return;
  int d = t & 31;
  int k = (t >> 5) % KMX;
  int i = t / (KMX * DD);
  int ik = i * KMX + k;
  float c = kcnt[ik];
  float val;
  if (c > 0.f) {
    val = sums[ik * DD + d] / fmaxf(c, 1.0f);
  } else {
    u32 n = ~(u32)(top5F[((size_t)(1 + iter) * LBN + i) * 5 + k]);
    if (n >= (u32)N) n = 0;
    int b = n / Z3, v = n - b * Z3;
    val = feats[((size_t)(b * DD + d)) * Z3 + v] * invn[n];
  }
  cent[ik * DD + d] = val;
}

__global__ void k_anchor_final(const float* __restrict__ cent, const float* __restrict__ sums,
                               const float* __restrict__ kcnt, const float* __restrict__ protn,
                               const int* __restrict__ labeled, float* __restrict__ accum) {
  int i = blockIdx.x;
  int d = threadIdx.x;
  if (d >= DD) return;  // lanes 0..31 of wave 0
  int c = labeled[i];
  float cnt = 0.f;
#pragma unroll
  for (int k = 0; k < KMX; ++k) cnt += kcnt[i * KMX + k];
  int cs = c < 0 ? 0 : (c > NCLS - 1 ? NCLS - 1 : c);
  float part = 0.f;
  if (cnt >= (float)KMX) {
    // kmeans branch: normalize twice
#pragma unroll
    for (int k = 0; k < KMX; ++k) {
      float v = cent[(i * KMX + k) * DD + d];
      float s = rsum32(v * v);
      float dn1 = sqrtf(s + 1e-12f);
      float v1 = v / dn1;
      float s2 = rsum32(v1 * v1);
      float dn2 = sqrtf(s2 + 1e-12f);
      float vv = v1 / dn2;
      float df = protn[(cs * KMX + k) * DD + d] - vv;
      part += df * df;
    }
  } else {
    float mv = 0.f;
#pragma unroll
    for (int k = 0; k < KMX; ++k) mv += sums[(i * KMX + k) * DD + d];
    mv /= fmaxf(cnt, 1.0f);
    float s = rsum32(mv * mv);
    float dn = sqrtf(s + 1e-12f);
    float vv = mv / dn;
#pragma unroll
    for (int k = 0; k < KMX; ++k) {
      float df = protn[(cs * KMX + k) * DD + d] - vv;
      part += df * df;
    }
  }
  float ls = rsum32(part) * (1.0f / (KMX * DD));
  bool valid = (c != 0) && (c < NCLS) && (cnt > 0.f);
  if (d == 0 && valid) { atomicAdd(&accum[0], ls); atomicAdd(&accum[1], 1.0f); }
}

__global__ void k_hist(const int* __restrict__ pseudo, RKeys RK, u32* __restrict__ hist,
                       const SelState* __restrict__ st, int pass, int N) {
  __shared__ u32 h[2048];
  for (int t = threadIdx.x; t < 2048; t += blockDim.x) h[t] = 0;
  __syncthreads();
  u32 half = (u32)(N / 2);
  u32 pre1 = 0, pre21 = 0;
  if (pass >= 1) pre1 = st->prefix1;
  if (pass == 2) pre21 = st->prefix21;
  int stride = gridDim.x * blockDim.x;
  for (int n = blockIdx.x * blockDim.x + threadIdx.x; n < N; n += stride) {
    if (pseudo[n] <= 0) continue;
    float g = jax_gumbel(RK.k1000[0], RK.k1000[1], half, (u32)n);
    u32 sv = f2sort(g);
    int bin = -1;
    if (pass == 0) bin = (int)(sv >> 21);
    else if (pass == 1) { if ((sv >> 21) == pre1) bin = (int)((sv >> 10) & 0x7FFu); }
    else { if ((sv >> 10) == pre21) bin = (int)(sv & 0x3FFu); }
    if (bin >= 0) atomicAdd(&h[bin], 1u);
  }
  __syncthreads();
  for (int t = threadIdx.x; t < 2048; t += blockDim.x) if (h[t]) atomicAdd(&hist[t], h[t]);
}

// parallel rank-search: find bin b with suffix_above(b) < rank <= suffix_above(b) + h[b]
__global__ void k_scan(const u32* __restrict__ hist, SelState* st, int pass) {
  __shared__ u32 h[2048];
  __shared__ u32 csum[256];
  __shared__ u32 sh_rank;
  __shared__ int sh_found;
  __shared__ u32 sh_rem;
  int tid = threadIdx.x;  // 256
  int nb = (pass == 2) ? 1024 : 2048;
  for (int t = tid; t < 2048; t += 256) h[t] = (t < nb) ? hist[t] : 0u;
  __syncthreads();
  u32 cs = 0;
#pragma unroll
  for (int j = 0; j < 8; ++j) cs += h[tid * 8 + j];
  csum[tid] = cs;
  __syncthreads();
  if (tid == 0) {
    if (pass == 0) {
      u64 tot = 0;
      for (int j = 0; j < 256; ++j) tot += csum[j];
      st->M = (u32)tot;
      u32 tgt = (u32)(tot < (u64)MAXA ? tot : (u64)MAXA);
      st->target = tgt;
      sh_rank = tgt;
    } else {
      sh_rank = (pass == 1) ? st->rank1 : st->rank2;
    }
    sh_found = -1;
    sh_rem = 0;
  }
  __syncthreads();
  u32 rank = sh_rank;
  if (rank > 0) {
    u32 above = 0;
    for (int j = tid + 1; j < 256; ++j) above += csum[j];
    u32 run = above;
    for (int b = tid * 8 + 7; b >= tid * 8; --b) {
      u32 c = h[b];
      if (run < rank && rank <= run + c) { sh_found = b; sh_rem = rank - run; }
      run += c;
    }
  }
  __syncthreads();
  if (tid == 0) {
    int found = sh_found;
    u32 rem = sh_rem;
    if (pass == 0) {
      if (found < 0) { st->prefix1 = 0xFFFFFFFFu; st->rank1 = 0; }
      else { st->prefix1 = (u32)found; st->rank1 = rem; }
    } else if (pass == 1) {
      if (found < 0) { st->prefix21 = 0xFFFFFFFFu; st->rank2 = 0; }
      else { st->prefix21 = (st->prefix1 << 11) | (u32)found; st->rank2 = rem; }
    } else {
      if (found < 0) st->pivot_sv = 0xFFFFFFFFu;
      else st->pivot_sv = (st->prefix21 << 10) | (u32)found;
    }
  }
}

__global__ void k_gather(const int* __restrict__ pseudo, RKeys RK, SelState* st,
                         u64* __restrict__ cand, int N) {
  if (st->target == 0) return;
  u32 piv = st->pivot_sv;
  u32 half = (u32)(N / 2);
  int stride = gridDim.x * blockDim.x;
  for (int n = blockIdx.x * blockDim.x + threadIdx.x; n < N; n += stride) {
    if (pseudo[n] <= 0) continue;
    float g = jax_gumbel(RK.k1000[0], RK.k1000[1], half, (u32)n);
    u32 sv = f2sort(g);
    if (sv >= piv) {
      u32 p = atomicAdd(&st->ncand, 1u);
      if (p < 4096u) cand[p] = ((u64)sv << 32) | (u32)(~(u32)n);
    }
  }
}

__global__ void __launch_bounds__(1024) k_sortsel(const u64* __restrict__ cand,
                                                  const SelState* __restrict__ st,
                                                  int* __restrict__ aidx) {
  __shared__ u64 s[4096];
  u32 nc = st->ncand; if (nc > 4096u) nc = 4096u;
  u32 target = st->target;
  for (int t = threadIdx.x; t < 4096; t += blockDim.x) s[t] = (t < (int)nc) ? cand[t] : 0ULL;
  __syncthreads();
  for (u32 ksz = 2; ksz <= 4096; ksz <<= 1) {
    for (u32 j = ksz >> 1; j > 0; j >>= 1) {
      for (u32 idx = threadIdx.x; idx < 4096; idx += blockDim.x) {
        u32 ixj = idx ^ j;
        if (ixj > idx) {
          bool up = (idx & ksz) == 0;
          u64 A = s[idx], B = s[ixj];
          bool sw = up ? (A < B) : (A > B);  // descending final order
          if (sw) { s[idx] = B; s[ixj] = A; }
        }
      }
      __syncthreads();
    }
  }
  for (int t = threadIdx.x; t < MAXA; t += blockDim.x)
    if (t < (int)target) aidx[t] = (int)(~(u32)s[t]);
}

__global__ void k_prep(const float* __restrict__ feats, const float* __restrict__ invn,
                       const int* __restrict__ pseudo, const SelState* __restrict__ st,
                       const int* __restrict__ aidx, float* __restrict__ afe,
                       int* __restrict__ alab, int N, int Z3) {
  int r = blockIdx.x * blockDim.x + threadIdx.x;
  if (r >= (int)st->target) return;
  int n = aidx[r];
  if ((u32)n >= (u32)N) n = 0;
  int lb = pseudo[n];
  lb = lb < 0 ? 0 : (lb > NCLS - 1 ? NCLS - 1 : lb);
  alab[r] = lb;
  int b = n / Z3, v = n - b * Z3;
  float inv = invn[n];
#pragma unroll
  for (int d = 0; d < DD; ++d)
    afe[(size_t)r * DD + d] = feats[((size_t)(b * DD + d)) * Z3 + v] * inv;
}

__global__ void k_triplet(const float* __restrict__ protn, const float* __restrict__ afe,
                          const int* __restrict__ alab, const SelState* __restrict__ st,
                          RKeys RK, float* __restrict__ acc) {
  __shared__ float pn[CKK * DD];
  __shared__ float spn[CKK];
  int tid = threadIdx.x;
  for (int t = tid; t < CKK * DD; t += blockDim.x) pn[t] = protn[t];
  __syncthreads();
  if (tid < CKK) {
    float s = 0.f;
    for (int d = 0; d < DD; ++d) s += pn[tid * DD + d] * pn[tid * DD + d];
    spn[tid] = s;
  }
  __syncthreads();
  int r = blockIdx.x * blockDim.x + tid;
  if (r >= (int)st->target) return;
  float a[DD]; float sa = 0.f;
#pragma unroll
  for (int d = 0; d < DD; ++d) { a[d] = afe[(size_t)r * DD + d]; sa += a[d] * a[d]; }
  int lab = alab[r];
  int ob = lab * KMX;
  float bs = -3.4e38f; int pidx = ob;
  float pos_d = 3.4e38f;
  for (int k = ob; k < ob + KMX; ++k) {
    float dot = 0.f;
#pragma unroll
    for (int d = 0; d < DD; ++d) dot += a[d] * pn[k * DD + d];
    if (dot > bs) { bs = dot; pidx = k; }
    float d2 = (sa + spn[k]) - 2.0f * dot;
    float dd = sqrtf(fmaxf(d2, 0.f));
    pos_d = fminf(pos_d, dd);
  }
  u32 halfT = (u32)(MAXA * CKK / 2);
  bool any_semi = false;
  float bg1 = -3.4e38f; int k1i = 0;
  float bg2 = -3.4e38f; int k2i = 0;
  for (int k = 0; k < CKK; ++k) {
    if (k / KMX == lab) continue;
    float dot = 0.f;
#pragma unroll
    for (int d = 0; d < DD; ++d) dot += a[d] * pn[k * DD + d];
    float d2 = (sa + spn[k]) - 2.0f * dot;
    float dd = sqrtf(fmaxf(d2, 0.f));
    u32 j = (u32)(r * CKK + k);
    bool semi = (dd > pos_d) && (dd < pos_d + 1.0f);
    if (semi) {
      float g1 = jax_gumbel(RK.k2000[0], RK.k2000[1], halfT, j);
      any_semi = true;
      if (g1 > bg1) { bg1 = g1; k1i = k; }
    }
    float g2 = jax_gumbel(RK.k2001[0], RK.k2001[1], halfT, j);
    if (g2 > bg2) { bg2 = g2; k2i = k; }
  }
  int nidx = any_semi ? k1i : k2i;
  float aden = sqrtf(sa + 1e-12f);
  float pden = sqrtf(spn[pidx] + 1e-12f);
  float nden = sqrtf(spn[nidx] + 1e-12f);
  float s1 = 0.f, s2 = 0.f;
#pragma unroll
  for (int d = 0; d < DD; ++d) {
    float an = a[d] / aden;
    float pv = pn[pidx * DD + d] / pden;
    float nv = pn[nidx * DD + d] / nden;
    float t1 = an - pv; s1 += t1 * t1;
    float t2 = an - nv; s2 += t2 * t2;
  }
  float d_pos = sqrtf(s1 + 1e-12f);
  float d_neg = sqrtf(s2 + 1e-12f);
  float xx = (d_pos - d_neg) + 1.0f;
  float l = fmaxf(xx, 0.f) + log1pf(expf(-fabsf(xx)));
  atomicAdd(&acc[0], l);
  atomicAdd(&acc[1], 1.0f);
}

__global__ void k_final(const float* __restrict__ anchor_acc, const float* __restrict__ proto_acc,
                        const float* __restrict__ compact, float* __restrict__ out) {
  if (threadIdx.x != 0 || blockIdx.x != 0) return;
  float al = anchor_acc[0] / fmaxf(anchor_acc[1], 1.0f);
  float pl = proto_acc[0] / fmaxf(proto_acc[1], 1.0f);
  out[0] = pl + 1.0f * al + 0.1f * compact[0];
}

// ---------------- host ----------------

static void host_keys(RKeys* K) {
  const u32 b0 = 0u, b1 = 42u;  // jax.random.key(42) -> [0, 42]
  u32 o0, o1;
  for (int i = 0; i < LBN; ++i) {
    u32 f0, f1;
    tf2x32(b0, b1, 0u, (u32)i, &f0, &f1);
    u32 p0, q0, p1, q1;
    tf2x32(f0, f1, 0u, 2u, &p0, &q0);
    tf2x32(f0, f1, 1u, 3u, &p1, &q1);
    K->ki[i][0] = p0; K->ki[i][1] = p1;
    K->kf[i][0] = q0; K->kf[i][1] = q1;
  }
  tf2x32(b0, b1, 0u, 1000u, &o0, &o1); K->k1000[0] = o0; K->k1000[1] = o1;
  tf2x32(b0, b1, 0u, 2000u, &o0, &o1); K->k2000[0] = o0; K->k2000[1] = o1;
  tf2x32(b0, b1, 0u, 2001u, &o0, &o1); K->k2001[0] = o0; K->k2001[1] = o1;
}

extern "C" void kernel_launch(void* const* d_in, const int* in_sizes, int n_in,
                              void* d_out, int out_size, void* d_ws, size_t ws_size,
                              hipStream_t stream) {
  const float* feats = (const float*)d_in[0];
  const float* protos = (const float*)d_in[1];
  const int* pseudo = (const int*)d_in[2];
  const int* gt = (const int*)d_in[3];
  const int* labeled = (const int*)d_in[4];
  float* out = (float*)d_out;

  int N = in_sizes[2];
  int Z3 = N / 4;  // B = 4 per setup_inputs

  RKeys RK;
  host_keys(&RK);

  char* W = (char*)d_ws;
  size_t off = 0;
  auto alloc = [&](size_t bytes) -> char* {
    char* p = W + off;
    off += (bytes + 255) & ~(size_t)255;
    return p;
  };
  float* invn = (float*)alloc((size_t)N * 4);
  char* stateBase = W + off;
  u64* top5A = (u64*)alloc((size_t)6 * LBN * NBLKA * 5 * 8);
  u64* top5F = (u64*)alloc((size_t)6 * LBN * 5 * 8);
  float* cent = (float*)alloc((size_t)LBN * KMX * DD * 4);
  float* sums = (float*)alloc((size_t)(LBN * KMX * DD + LBN * KMX) * 4);
  float* kcnt = sums + LBN * KMX * DD;
  float* protn = (float*)alloc((size_t)CKK * DD * 4);
  float* compact = (float*)alloc(256);
  float* anchor_acc = (float*)alloc(256);
  float* proto_acc = (float*)alloc(256);
  u32* hist = (u32*)alloc(2048 * 4);
  SelState* st = (SelState*)alloc(256);
  u64* cand = (u64*)alloc(4096 * 8);
  int* aidx = (int*)alloc((size_t)MAXA * 4);
  int* alab = (int*)alloc((size_t)MAXA * 4);
  float* afe = (float*)alloc((size_t)MAXA * DD * 4);
  if (ws_size < off) return;

  size_t stateBytes = (size_t)((W + off) - stateBase);
  hipMemsetAsync(stateBase, 0, stateBytes, stream);

  k_invnorm<<<dim3((N + 255) / 256), dim3(256), 0, stream>>>(feats, invn, N, Z3);
  k_protos<<<dim3(1), dim3(256), 0, stream>>>(protos, protn, compact);

  k_top5A<<<dim3(NBLKA, 6, LBN), dim3(256), 0, stream>>>(gt, labeled, RK, top5A, N);
  k_top5B<<<dim3(6, LBN), dim3(256), 0, stream>>>(top5A, top5F, NBLKA);

  k_initcent<<<dim3(1), dim3(LBN * KMX * DD), 0, stream>>>(feats, invn, top5F, cent, N, Z3);
  for (int it = 0; it < KIT; ++it) {
    hipMemsetAsync(sums, 0, (size_t)(LBN * KMX * DD + LBN * KMX) * 4, stream);
    k_assign<<<dim3(1024), dim3(256), 0, stream>>>(feats, invn, gt, labeled, cent, sums, kcnt, N, Z3);
    k_update<<<dim3(1), dim3(LBN * KMX * DD), 0, stream>>>(feats, invn, top5F, sums, kcnt, cent, it, N, Z3);
  }
  k_anchor_final<<<dim3(LBN), dim3(64), 0, stream>>>(cent, sums, kcnt, protn, labeled, anchor_acc);

  k_hist<<<dim3(1024), dim3(256), 0, stream>>>(pseudo, RK, hist, st, 0, N);
  k_scan<<<dim3(1), dim3(256), 0, stream>>>(hist, st, 0);
  hipMemsetAsync(hist, 0, 2048 * 4, stream);
  k_hist<<<dim3(1024), dim3(256), 0, stream>>>(pseudo, RK, hist, st, 1, N);
  k_scan<<<dim3(1), dim3(256), 0, stream>>>(hist, st, 1);
  hipMemsetAsync(hist, 0, 2048 * 4, stream);
  k_hist<<<dim3(1024), dim3(256), 0, stream>>>(pseudo, RK, hist, st, 2, N);
  k_scan<<<dim3(1), dim3(256), 0, stream>>>(hist, st, 2);
  k_gather<<<dim3(1024), dim3(256), 0, stream>>>(pseudo, RK, st, cand, N);
  k_sortsel<<<dim3(1), dim3(1024), 0, stream>>>(cand, st, aidx);

  k_prep<<<dim3(MAXA / 256), dim3(256), 0, stream>>>(feats, invn, pseudo, st, aidx, afe, alab, N, Z3);
  k_triplet<<<dim3(MAXA / 256), dim3(256), 0, stream>>>(protn, afe, alab, st, RK, proto_acc);

  k_final<<<dim3(1), dim3(64), 0, stream>>>(anchor_acc, proto_acc, compact, out);
}

// Round 3
// 1154.578 us; speedup vs baseline: 1.6919x; 1.1926x over previous
//
#include <hip/hip_runtime.h>
#include <stdint.h>

typedef unsigned int u32;
typedef unsigned long long u64;

#define NCLS 5
#define KMX 5
#define DD 32
#define LBN 4
#define KIT 5
#define MAXA 2048
#define CKK 25
#define NBLKA 64
#define CPAD 36
#define FTINY 1.17549435e-38f

struct RKeys {
  u32 ki[LBN][2];
  u32 kf[LBN][2];
  u32 k1000[2];
  u32 k2000[2];
  u32 k2001[2];
};

struct SelState {
  u32 prefix1, rank1, prefix21, rank2, pivot_sv, target, M, ncand;
};

// ---------------- threefry2x32 (bit-exact JAX) ----------------
__host__ __device__ inline void tf2x32(u32 k0, u32 k1, u32 x0, u32 x1, u32* o0, u32* o1) {
  u32 ks2 = k0 ^ k1 ^ 0x1BD11BDAu;
  u32 ks[3] = {k0, k1, ks2};
  x0 += k0; x1 += k1;
  const int rotA[4] = {13, 15, 26, 6};
  const int rotB[4] = {17, 29, 16, 24};
#pragma unroll
  for (int g = 0; g < 5; ++g) {
#pragma unroll
    for (int j = 0; j < 4; ++j) {
      int r = (g & 1) ? rotB[j] : rotA[j];
      x0 += x1;
      x1 = (x1 << r) | (x1 >> (32 - r));
      x1 ^= x0;
    }
    x0 += ks[(g + 1) % 3];
    x1 += ks[(g + 2) % 3] + (u32)(g + 1);
  }
  *o0 = x0; *o1 = x1;
}

__device__ inline float jax_gumbel(u32 k0, u32 k1, u32 half, u32 idx) {
  bool hi = (idx >= half);
  u32 c0 = hi ? (idx - half) : idx;
  u32 c1 = hi ? idx : (idx + half);
  u32 o0, o1;
  tf2x32(k0, k1, c0, c1, &o0, &o1);
  u32 bits = hi ? o1 : o0;
  u32 fb = (bits >> 9) | 0x3F800000u;
  float f = __uint_as_float(fb) - 1.0f;
  float u = (f == 0.0f) ? FTINY : f;
  return -logf(-logf(u));
}

__device__ inline u32 f2sort(float f) {
  u32 b = __float_as_uint(f);
  return (b & 0x80000000u) ? ~b : (b | 0x80000000u);
}

#define INS5(kk, a0, a1, a2, a3, a4) do { u64 _k = (kk); \
  if (_k > a4) { a4 = _k; u64 _t; \
    if (a4 > a3) { _t = a3; a3 = a4; a4 = _t; } \
    if (a3 > a2) { _t = a2; a2 = a3; a3 = _t; } \
    if (a2 > a1) { _t = a1; a1 = a2; a2 = _t; } \
    if (a1 > a0) { _t = a0; a0 = a1; a1 = _t; } } } while (0)

#define WMERGE5(off, a0, a1, a2, a3, a4) do { \
  u64 r0 = __shfl_xor(a0, off, 64), r1 = __shfl_xor(a1, off, 64), \
      r2 = __shfl_xor(a2, off, 64), r3 = __shfl_xor(a3, off, 64), \
      r4 = __shfl_xor(a4, off, 64); \
  INS5(r0, a0, a1, a2, a3, a4); INS5(r1, a0, a1, a2, a3, a4); \
  INS5(r2, a0, a1, a2, a3, a4); INS5(r3, a0, a1, a2, a3, a4); \
  INS5(r4, a0, a1, a2, a3, a4); } while (0)

#define WMERGE_ALL(a0,a1,a2,a3,a4) do { \
  WMERGE5(32,a0,a1,a2,a3,a4); WMERGE5(16,a0,a1,a2,a3,a4); WMERGE5(8,a0,a1,a2,a3,a4); \
  WMERGE5(4,a0,a1,a2,a3,a4); WMERGE5(2,a0,a1,a2,a3,a4); WMERGE5(1,a0,a1,a2,a3,a4); } while (0)

__device__ inline float rsum32(float v) {
#pragma unroll
  for (int o = 16; o; o >>= 1) v += __shfl_xor(v, o, 32);
  return v;
}

// ---------------- kernels ----------------

__global__ void k_protos(const float* __restrict__ protos, float* __restrict__ protn, float* __restrict__ compact) {
  __shared__ float pl[CKK * DD];
  __shared__ float rn[CKK];
  __shared__ float red[4];
  int tid = threadIdx.x;  // 256
  for (int t = tid; t < CKK * DD; t += 256) pl[t] = protos[t];
  __syncthreads();
  if (tid < CKK) {
    float s = 0.f;
    for (int d = 0; d < DD; ++d) { float x = pl[tid * DD + d]; s += x * x; }
    rn[tid] = sqrtf(s + 1e-12f);
  }
  __syncthreads();
  for (int t = tid; t < CKK * DD; t += 256) {
    float v = pl[t] / rn[t / DD];
    pl[t] = v;
    protn[t] = v;
  }
  __syncthreads();
  float part = 0.f;
  if (tid < (NCLS - 1) * DD) {
    int c = 1 + tid / DD;
    int d = tid % DD;
    float m = 0.f;
#pragma unroll
    for (int k = 0; k < KMX; ++k) m += pl[(c * KMX + k) * DD + d];
    m *= (1.0f / KMX);
    float v = 0.f;
#pragma unroll
    for (int k = 0; k < KMX; ++k) { float df = pl[(c * KMX + k) * DD + d] - m; v += df * df; }
    part = v * (1.0f / (KMX - 1)) * (1.0f / DD);
  }
#pragma unroll
  for (int o = 32; o; o >>= 1) part += __shfl_xor(part, o, 64);
  int wid = tid >> 6;
  if ((tid & 63) == 0) red[wid] = part;
  __syncthreads();
  if (tid == 0) compact[0] = red[0] + red[1] + red[2] + red[3];
}

// merged: one scan per kind covers all 4 classes (per-lane class index)
__global__ void k_top5A(const int* __restrict__ gt, const int* __restrict__ labeled,
                        RKeys RK, u64* __restrict__ outA, int N) {
  int kind = blockIdx.y;
  int lb0 = labeled[0], lb1 = labeled[1], lb2 = labeled[2], lb3 = labeled[3];
  u32 half = (kind == 0) ? (u32)(N / 2) : (u32)(((u64)5 * (u64)N) / 2);
  u32 base = (kind == 0) ? 0u : (u32)((u64)(kind - 1) * (u64)N);
  u32 ka0 = (kind == 0) ? RK.ki[0][0] : RK.kf[0][0], kb0 = (kind == 0) ? RK.ki[0][1] : RK.kf[0][1];
  u32 ka1 = (kind == 0) ? RK.ki[1][0] : RK.kf[1][0], kb1 = (kind == 0) ? RK.ki[1][1] : RK.kf[1][1];
  u32 ka2 = (kind == 0) ? RK.ki[2][0] : RK.kf[2][0], kb2 = (kind == 0) ? RK.ki[2][1] : RK.kf[2][1];
  u32 ka3 = (kind == 0) ? RK.ki[3][0] : RK.kf[3][0], kb3 = (kind == 0) ? RK.ki[3][1] : RK.kf[3][1];
  u64 A0=0,A1=0,A2=0,A3=0,A4=0;
  u64 B0=0,B1=0,B2=0,B3=0,B4=0;
  u64 C0=0,C1=0,C2=0,C3=0,C4=0;
  u64 D0=0,D1=0,D2=0,D3=0,D4=0;
  int stride = gridDim.x * blockDim.x;
  for (int n = blockIdx.x * blockDim.x + threadIdx.x; n < N; n += stride) {
    int g = gt[n];
    int ci = (g == lb0) ? 0 : (g == lb1) ? 1 : (g == lb2) ? 2 : (g == lb3) ? 3 : -1;
    if (ci < 0) continue;
    u32 k0 = (ci & 2) ? ((ci & 1) ? ka3 : ka2) : ((ci & 1) ? ka1 : ka0);
    u32 k1 = (ci & 2) ? ((ci & 1) ? kb3 : kb2) : ((ci & 1) ? kb1 : kb0);
    float gv = jax_gumbel(k0, k1, half, base + (u32)n);
    u64 key = ((u64)f2sort(gv) << 32) | (u32)(~(u32)n);
    if (ci == 0) { INS5(key, A0, A1, A2, A3, A4); }
    else if (ci == 1) { INS5(key, B0, B1, B2, B3, B4); }
    else if (ci == 2) { INS5(key, C0, C1, C2, C3, C4); }
    else { INS5(key, D0, D1, D2, D3, D4); }
  }
  WMERGE_ALL(A0,A1,A2,A3,A4);
  WMERGE_ALL(B0,B1,B2,B3,B4);
  WMERGE_ALL(C0,C1,C2,C3,C4);
  WMERGE_ALL(D0,D1,D2,D3,D4);
  __shared__ u64 wbuf[4][20];
  int tid = threadIdx.x;
  int wid = tid >> 6;
  if ((tid & 63) == 0) {
    u64* w = wbuf[wid];
    w[0]=A0; w[1]=A1; w[2]=A2; w[3]=A3; w[4]=A4;
    w[5]=B0; w[6]=B1; w[7]=B2; w[8]=B3; w[9]=B4;
    w[10]=C0; w[11]=C1; w[12]=C2; w[13]=C3; w[14]=C4;
    w[15]=D0; w[16]=D1; w[17]=D2; w[18]=D3; w[19]=D4;
  }
  __syncthreads();
  if (tid == 0) {
#pragma unroll
    for (int w = 1; w < 4; ++w) {
#pragma unroll
      for (int j = 0; j < 5; ++j) {
        u64 ka = wbuf[w][j];      INS5(ka, A0, A1, A2, A3, A4);
        u64 kb = wbuf[w][5 + j];  INS5(kb, B0, B1, B2, B3, B4);
        u64 kc = wbuf[w][10 + j]; INS5(kc, C0, C1, C2, C3, C4);
        u64 kd = wbuf[w][15 + j]; INS5(kd, D0, D1, D2, D3, D4);
      }
    }
    size_t nb = gridDim.x;
    u64* o0 = outA + (((size_t)kind * LBN + 0) * nb + blockIdx.x) * 5;
    o0[0]=A0; o0[1]=A1; o0[2]=A2; o0[3]=A3; o0[4]=A4;
    u64* o1 = outA + (((size_t)kind * LBN + 1) * nb + blockIdx.x) * 5;
    o1[0]=B0; o1[1]=B1; o1[2]=B2; o1[3]=B3; o1[4]=B4;
    u64* o2 = outA + (((size_t)kind * LBN + 2) * nb + blockIdx.x) * 5;
    o2[0]=C0; o2[1]=C1; o2[2]=C2; o2[3]=C3; o2[4]=C4;
    u64* o3 = outA + (((size_t)kind * LBN + 3) * nb + blockIdx.x) * 5;
    o3[0]=D0; o3[1]=D1; o3[2]=D2; o3[3]=D3; o3[4]=D4;
  }
}

__global__ void k_top5B(const u64* __restrict__ outA, u64* __restrict__ top5F, int nblk) {
  int kind = blockIdx.x;
  int i = blockIdx.y;
  const u64* src = outA + ((size_t)kind * LBN + i) * nblk * 5;
  u64 t0 = 0, t1 = 0, t2 = 0, t3 = 0, t4 = 0;
  int tot = nblk * 5;
  for (int j = threadIdx.x; j < tot; j += blockDim.x) { u64 k = src[j]; INS5(k, t0, t1, t2, t3, t4); }
  WMERGE_ALL(t0, t1, t2, t3, t4);
  __shared__ u64 wbuf[4 * 5];
  int tid = threadIdx.x;
  int wid = tid >> 6;
  if ((tid & 63) == 0) {
    wbuf[wid * 5 + 0] = t0; wbuf[wid * 5 + 1] = t1; wbuf[wid * 5 + 2] = t2;
    wbuf[wid * 5 + 3] = t3; wbuf[wid * 5 + 4] = t4;
  }
  __syncthreads();
  if (tid == 0) {
#pragma unroll
    for (int w = 1; w < 4; ++w)
#pragma unroll
      for (int j = 0; j < 5; ++j) { u64 k = wbuf[w * 5 + j]; INS5(k, t0, t1, t2, t3, t4); }
    u64* o = top5F + ((size_t)kind * LBN + i) * 5;
    o[0] = t0; o[1] = t1; o[2] = t2; o[3] = t3; o[4] = t4;
  }
}

__global__ void k_initcent(const float* __restrict__ feats,
                           const u64* __restrict__ top5F, float* __restrict__ cent, int N, int Z3) {
  int t = threadIdx.x;
  if (t >= LBN * KMX * DD) return;
  int d = t & 31;
  int k = (t >> 5) % KMX;
  int i = t / (KMX * DD);
  u32 n = ~(u32)(top5F[((size_t)0 * LBN + i) * 5 + k]);
  if (n >= (u32)N) n = 0;
  int b = n / Z3, v = n - b * Z3;
  const float* fp = feats + (size_t)b * DD * Z3 + v;
  float sa = 0.f, xd = 0.f;
#pragma unroll
  for (int dd = 0; dd < DD; ++dd) { float x = fp[(size_t)dd * Z3]; sa += x * x; if (dd == d) xd = x; }
  cent[(i * KMX + k) * DD + d] = xd * (1.0f / sqrtf(sa + 1e-12f));
}

__device__ inline void vox_accum(const float* x, float san, int ci,
                                 const float* sc, const float* scn,
                                 float* ssum, float* scnt) {
  if (ci < 0) return;
  int basec = ci * KMX;
  float bestd = 3.4e38f; int bk = 0;
#pragma unroll
  for (int k = 0; k < KMX; ++k) {
    const float* cp = sc + (basec + k) * CPAD;
    float dot = 0.f;
#pragma unroll
    for (int q = 0; q < 8; ++q) {
      float4 c4 = *(const float4*)(cp + q * 4);
      dot += x[q*4+0]*c4.x + x[q*4+1]*c4.y + x[q*4+2]*c4.z + x[q*4+3]*c4.w;
    }
    float d2 = (san + scn[basec + k]) - 2.0f * dot;  // argmin(sqrt(d2)) == argmin(d2)
    if (d2 < bestd) { bestd = d2; bk = k; }
  }
  int cl = basec + bk;
  atomicAdd(&scnt[cl], 1.0f);
  float* dst = ssum + cl * CPAD;
#pragma unroll
  for (int d = 0; d < DD; ++d) atomicAdd(&dst[d], x[d]);
}

__global__ void k_assign(const float* __restrict__ feats,
                         const int* __restrict__ gt, const int* __restrict__ labeled,
                         const float* __restrict__ cent, float* __restrict__ sums,
                         float* __restrict__ kcnt, int N, int Z3) {
  __shared__ float sc[CKK * CPAD];      // only first 20 used; padded stride
  __shared__ float ssum[CKK * CPAD];
  __shared__ float scn[LBN * KMX];
  __shared__ float scnt[LBN * KMX];
  int tid = threadIdx.x;
  for (int t = tid; t < LBN * KMX * DD; t += 256) {
    int cl = t >> 5, d = t & 31;
    sc[cl * CPAD + d] = cent[t];
  }
  for (int t = tid; t < LBN * KMX * CPAD; t += 256) ssum[t] = 0.f;
  if (tid < LBN * KMX) scnt[tid] = 0.f;
  __syncthreads();
  if (tid < LBN * KMX) {
    float s = 0.f;
#pragma unroll
    for (int d = 0; d < DD; ++d) { float c = sc[tid * CPAD + d]; s += c * c; }
    scn[tid] = s;
  }
  __syncthreads();
  int lb0 = labeled[0], lb1 = labeled[1], lb2 = labeled[2], lb3 = labeled[3];

  int t = blockIdx.x * blockDim.x + tid;
  int n0 = 2 * t;
  if (n0 < N) {
    if (n0 + 1 < N) {
      int2 gg = *(const int2*)(gt + n0);
      int cia = (gg.x == lb0) ? 0 : (gg.x == lb1) ? 1 : (gg.x == lb2) ? 2 : (gg.x == lb3) ? 3 : -1;
      int cib = (gg.y == lb0) ? 0 : (gg.y == lb1) ? 1 : (gg.y == lb2) ? 2 : (gg.y == lb3) ? 3 : -1;
      if (cia >= 0 || cib >= 0) {
        int b = n0 / Z3, v = n0 - b * Z3;  // Z3 even, pair stays in one b
        const float* fp = feats + (size_t)b * DD * Z3 + v;
        float xa[DD], xb[DD];
        float sra = 0.f, srb = 0.f;
#pragma unroll
        for (int d = 0; d < DD; ++d) {
          float2 f2 = *(const float2*)(fp + (size_t)d * Z3);
          xa[d] = f2.x; xb[d] = f2.y;
          sra += f2.x * f2.x; srb += f2.y * f2.y;
        }
        float inva = 1.0f / sqrtf(sra + 1e-12f);
        float invb = 1.0f / sqrtf(srb + 1e-12f);
        float sana = 0.f, sanb = 0.f;
#pragma unroll
        for (int d = 0; d < DD; ++d) {
          xa[d] *= inva; sana += xa[d] * xa[d];
          xb[d] *= invb; sanb += xb[d] * xb[d];
        }
        vox_accum(xa, sana, cia, sc, scn, ssum, scnt);
        vox_accum(xb, sanb, cib, sc, scn, ssum, scnt);
      }
    } else {
      int g = gt[n0];
      int ci = (g == lb0) ? 0 : (g == lb1) ? 1 : (g == lb2) ? 2 : (g == lb3) ? 3 : -1;
      if (ci >= 0) {
        int b = n0 / Z3, v = n0 - b * Z3;
        const float* fp = feats + (size_t)b * DD * Z3 + v;
        float x[DD]; float sr = 0.f;
#pragma unroll
        for (int d = 0; d < DD; ++d) { x[d] = fp[(size_t)d * Z3]; sr += x[d] * x[d]; }
        float inv = 1.0f / sqrtf(sr + 1e-12f);
        float san = 0.f;
#pragma unroll
        for (int d = 0; d < DD; ++d) { x[d] *= inv; san += x[d] * x[d]; }
        vox_accum(x, san, ci, sc, scn, ssum, scnt);
      }
    }
  }
  __syncthreads();
  for (int q = tid; q < LBN * KMX * DD; q += 256) {
    int cl = q >> 5, d = q & 31;
    float v = ssum[cl * CPAD + d];
    if (v != 0.f) atomicAdd(&sums[q], v);
  }
  if (tid < LBN * KMX && scnt[tid] != 0.f) atomicAdd(&kcnt[tid], scnt[tid]);
}

__global__ void k_update(const float* __restrict__ feats,
                         const u64* __restrict__ top5F, const float* __restrict__ sums,
                         const float* __restrict__ kcnt, float* __restrict__ cent,
                         int iter, int N, int Z3) {
  int t = threadIdx.x;
  if (t >= LBN * KMX * DD) return;
  int d = t & 31;
  int k = (t >> 5) % KMX;
  int i = t / (KMX * DD);
  int ik = i * KMX + k;
  float c = kcnt[ik];
  float val;
  if (c > 0.f) {
    val = sums[ik * DD + d] / fmaxf(c, 1.0f);
  } else {
    u32 n = ~(u32)(top5F[((size_t)(1 + iter) * LBN + i) * 5 + k]);
    if (n >= (u32)N) n = 0;
    int b = n / Z3, v = n - b * Z3;
    const float* fp = feats + (size_t)b * DD * Z3 + v;
    float sa = 0.f, xd = 0.f;
#pragma unroll
    for (int dd = 0; dd < DD; ++dd) { float x = fp[(size_t)dd * Z3]; sa += x * x; if (dd == d) xd = x; }
    val = xd * (1.0f / sqrtf(sa + 1e-12f));
  }
  cent[ik * DD + d] = val;
}

__global__ void k_anchor_final(const float* __restrict__ cent, const float* __restrict__ sums,
                               const float* __restrict__ kcnt, const float* __restrict__ protn,
                               const int* __restrict__ labeled, float* __restrict__ accum) {
  int i = blockIdx.x;
  int d = threadIdx.x;
  if (d >= DD) return;
  int c = labeled[i];
  float cnt = 0.f;
#pragma unroll
  for (int k = 0; k < KMX; ++k) cnt += kcnt[i * KMX + k];
  int cs = c < 0 ? 0 : (c > NCLS - 1 ? NCLS - 1 : c);
  float part = 0.f;
  if (cnt >= (float)KMX) {
#pragma unroll
    for (int k = 0; k < KMX; ++k) {
      float v = cent[(i * KMX + k) * DD + d];
      float s = rsum32(v * v);
      float dn1 = sqrtf(s + 1e-12f);
      float v1 = v / dn1;
      float s2 = rsum32(v1 * v1);
      float dn2 = sqrtf(s2 + 1e-12f);
      float vv = v1 / dn2;
      float df = protn[(cs * KMX + k) * DD + d] - vv;
      part += df * df;
    }
  } else {
    float mv = 0.f;
#pragma unroll
    for (int k = 0; k < KMX; ++k) mv += sums[(i * KMX + k) * DD + d];
    mv /= fmaxf(cnt, 1.0f);
    float s = rsum32(mv * mv);
    float dn = sqrtf(s + 1e-12f);
    float vv = mv / dn;
#pragma unroll
    for (int k = 0; k < KMX; ++k) {
      float df = protn[(cs * KMX + k) * DD + d] - vv;
      part += df * df;
    }
  }
  float ls = rsum32(part) * (1.0f / (KMX * DD));
  bool valid = (c != 0) && (c < NCLS) && (cnt > 0.f);
  if (d == 0 && valid) { atomicAdd(&accum[0], ls); atomicAdd(&accum[1], 1.0f); }
}

__global__ void k_hist(const int* __restrict__ pseudo, RKeys RK, u32* __restrict__ hist,
                       const SelState* __restrict__ st, int pass, int N) {
  __shared__ u32 h[2048];
  for (int t = threadIdx.x; t < 2048; t += blockDim.x) h[t] = 0;
  __syncthreads();
  u32 half = (u32)(N / 2);
  u32 pre1 = 0, pre21 = 0;
  if (pass >= 1) pre1 = st->prefix1;
  if (pass == 2) pre21 = st->prefix21;
  int stride = gridDim.x * blockDim.x;
  for (int n = blockIdx.x * blockDim.x + threadIdx.x; n < N; n += stride) {
    if (pseudo[n] <= 0) continue;
    float g = jax_gumbel(RK.k1000[0], RK.k1000[1], half, (u32)n);
    u32 sv = f2sort(g);
    int bin = -1;
    if (pass == 0) bin = (int)(sv >> 21);
    else if (pass == 1) { if ((sv >> 21) == pre1) bin = (int)((sv >> 10) & 0x7FFu); }
    else { if ((sv >> 10) == pre21) bin = (int)(sv & 0x3FFu); }
    if (bin >= 0) atomicAdd(&h[bin], 1u);
  }
  __syncthreads();
  for (int t = threadIdx.x; t < 2048; t += blockDim.x) if (h[t]) atomicAdd(&hist[t], h[t]);
}

__global__ void k_scan(const u32* __restrict__ hist, SelState* st, int pass) {
  __shared__ u32 h[2048];
  __shared__ u32 csum[256];
  __shared__ u32 sh_rank;
  __shared__ int sh_found;
  __shared__ u32 sh_rem;
  int tid = threadIdx.x;  // 256
  int nb = (pass == 2) ? 1024 : 2048;
  for (int t = tid; t < 2048; t += 256) h[t] = (t < nb) ? hist[t] : 0u;
  __syncthreads();
  u32 cs = 0;
#pragma unroll
  for (int j = 0; j < 8; ++j) cs += h[tid * 8 + j];
  csum[tid] = cs;
  __syncthreads();
  if (tid == 0) {
    if (pass == 0) {
      u64 tot = 0;
      for (int j = 0; j < 256; ++j) tot += csum[j];
      st->M = (u32)tot;
      u32 tgt = (u32)(tot < (u64)MAXA ? tot : (u64)MAXA);
      st->target = tgt;
      sh_rank = tgt;
    } else {
      sh_rank = (pass == 1) ? st->rank1 : st->rank2;
    }
    sh_found = -1;
    sh_rem = 0;
  }
  __syncthreads();
  u32 rank = sh_rank;
  if (rank > 0) {
    u32 above = 0;
    for (int j = tid + 1; j < 256; ++j) above += csum[j];
    u32 run = above;
    for (int b = tid * 8 + 7; b >= tid * 8; --b) {
      u32 c = h[b];
      if (run < rank && rank <= run + c) { sh_found = b; sh_rem = rank - run; }
      run += c;
    }
  }
  __syncthreads();
  if (tid == 0) {
    int found = sh_found;
    u32 rem = sh_rem;
    if (pass == 0) {
      if (found < 0) { st->prefix1 = 0xFFFFFFFFu; st->rank1 = 0; }
      else { st->prefix1 = (u32)found; st->rank1 = rem; }
    } else if (pass == 1) {
      if (found < 0) { st->prefix21 = 0xFFFFFFFFu; st->rank2 = 0; }
      else { st->prefix21 = (st->prefix1 << 11) | (u32)found; st->rank2 = rem; }
    } else {
      if (found < 0) st->pivot_sv = 0xFFFFFFFFu;
      else st->pivot_sv = (st->prefix21 << 10) | (u32)found;
    }
  }
}

__global__ void k_gather(const int* __restrict__ pseudo, RKeys RK, SelState* st,
                         u64* __restrict__ cand, int N) {
  if (st->target == 0) return;
  u32 piv = st->pivot_sv;
  u32 half = (u32)(N / 2);
  int stride = gridDim.x * blockDim.x;
  for (int n = blockIdx.x * blockDim.x + threadIdx.x; n < N; n += stride) {
    if (pseudo[n] <= 0) continue;
    float g = jax_gumbel(RK.k1000[0], RK.k1000[1], half, (u32)n);
    u32 sv = f2sort(g);
    if (sv >= piv) {
      u32 p = atomicAdd(&st->ncand, 1u);
      if (p < 4096u) cand[p] = ((u64)sv << 32) | (u32)(~(u32)n);
    }
  }
}

__global__ void __launch_bounds__(1024) k_sortsel(const u64* __restrict__ cand,
                                                  const SelState* __restrict__ st,
                                                  int* __restrict__ aidx) {
  __shared__ u64 s[4096];
  u32 nc = st->ncand; if (nc > 4096u) nc = 4096u;
  u32 target = st->target;
  for (int t = threadIdx.x; t < 4096; t += blockDim.x) s[t] = (t < (int)nc) ? cand[t] : 0ULL;
  __syncthreads();
  for (u32 ksz = 2; ksz <= 4096; ksz <<= 1) {
    for (u32 j = ksz >> 1; j > 0; j >>= 1) {
      for (u32 idx = threadIdx.x; idx < 4096; idx += blockDim.x) {
        u32 ixj = idx ^ j;
        if (ixj > idx) {
          bool up = (idx & ksz) == 0;
          u64 A = s[idx], B = s[ixj];
          bool sw = up ? (A < B) : (A > B);
          if (sw) { s[idx] = B; s[ixj] = A; }
        }
      }
      __syncthreads();
    }
  }
  for (int t = threadIdx.x; t < MAXA; t += blockDim.x)
    if (t < (int)target) aidx[t] = (int)(~(u32)s[t]);
}

__global__ void k_prep(const float* __restrict__ feats,
                       const int* __restrict__ pseudo, const SelState* __restrict__ st,
                       const int* __restrict__ aidx, float* __restrict__ afe,
                       int* __restrict__ alab, int N, int Z3) {
  int r = blockIdx.x * blockDim.x + threadIdx.x;
  if (r >= (int)st->target) return;
  int n = aidx[r];
  if ((u32)n >= (u32)N) n = 0;
  int lb = pseudo[n];
  lb = lb < 0 ? 0 : (lb > NCLS - 1 ? NCLS - 1 : lb);
  alab[r] = lb;
  int b = n / Z3, v = n - b * Z3;
  const float* fp = feats + (size_t)b * DD * Z3 + v;
  float x[DD]; float sr = 0.f;
#pragma unroll
  for (int d = 0; d < DD; ++d) { x[d] = fp[(size_t)d * Z3]; sr += x[d] * x[d]; }
  float inv = 1.0f / sqrtf(sr + 1e-12f);
#pragma unroll
  for (int d = 0; d < DD; ++d) afe[(size_t)r * DD + d] = x[d] * inv;
}

__global__ void k_triplet(const float* __restrict__ protn, const float* __restrict__ afe,
                          const int* __restrict__ alab, const SelState* __restrict__ st,
                          RKeys RK, float* __restrict__ acc) {
  __shared__ float pn[CKK * DD];
  __shared__ float spn[CKK];
  int tid = threadIdx.x;
  for (int t = tid; t < CKK * DD; t += blockDim.x) pn[t] = protn[t];
  __syncthreads();
  if (tid < CKK) {
    float s = 0.f;
    for (int d = 0; d < DD; ++d) s += pn[tid * DD + d] * pn[tid * DD + d];
    spn[tid] = s;
  }
  __syncthreads();
  int r = blockIdx.x * blockDim.x + tid;
  if (r >= (int)st->target) return;
  float a[DD]; float sa = 0.f;
#pragma unroll
  for (int d = 0; d < DD; ++d) { a[d] = afe[(size_t)r * DD + d]; sa += a[d] * a[d]; }
  int lab = alab[r];
  int ob = lab * KMX;
  float bs = -3.4e38f; int pidx = ob;
  float pos_d = 3.4e38f;
  for (int k = ob; k < ob + KMX; ++k) {
    float dot = 0.f;
#pragma unroll
    for (int d = 0; d < DD; ++d) dot += a[d] * pn[k * DD + d];
    if (dot > bs) { bs = dot; pidx = k; }
    float d2 = (sa + spn[k]) - 2.0f * dot;
    float dd = sqrtf(fmaxf(d2, 0.f));
    pos_d = fminf(pos_d, dd);
  }
  u32 halfT = (u32)(MAXA * CKK / 2);
  bool any_semi = false;
  float bg1 = -3.4e38f; int k1i = 0;
  float bg2 = -3.4e38f; int k2i = 0;
  for (int k = 0; k < CKK; ++k) {
    if (k / KMX == lab) continue;
    float dot = 0.f;
#pragma unroll
    for (int d = 0; d < DD; ++d) dot += a[d] * pn[k * DD + d];
    float d2 = (sa + spn[k]) - 2.0f * dot;
    float dd = sqrtf(fmaxf(d2, 0.f));
    u32 j = (u32)(r * CKK + k);
    bool semi = (dd > pos_d) && (dd < pos_d + 1.0f);
    if (semi) {
      float g1 = jax_gumbel(RK.k2000[0], RK.k2000[1], halfT, j);
      any_semi = true;
      if (g1 > bg1) { bg1 = g1; k1i = k; }
    }
    float g2 = jax_gumbel(RK.k2001[0], RK.k2001[1], halfT, j);
    if (g2 > bg2) { bg2 = g2; k2i = k; }
  }
  int nidx = any_semi ? k1i : k2i;
  float aden = sqrtf(sa + 1e-12f);
  float pden = sqrtf(spn[pidx] + 1e-12f);
  float nden = sqrtf(spn[nidx] + 1e-12f);
  float s1 = 0.f, s2 = 0.f;
#pragma unroll
  for (int d = 0; d < DD; ++d) {
    float an = a[d] / aden;
    float pv = pn[pidx * DD + d] / pden;
    float nv = pn[nidx * DD + d] / nden;
    float t1 = an - pv; s1 += t1 * t1;
    float t2 = an - nv; s2 += t2 * t2;
  }
  float d_pos = sqrtf(s1 + 1e-12f);
  float d_neg = sqrtf(s2 + 1e-12f);
  float xx = (d_pos - d_neg) + 1.0f;
  float l = fmaxf(xx, 0.f) + log1pf(expf(-fabsf(xx)));
  atomicAdd(&acc[0], l);
  atomicAdd(&acc[1], 1.0f);
}

__global__ void k_final(const float* __restrict__ anchor_acc, const float* __restrict__ proto_acc,
                        const float* __restrict__ compact, float* __restrict__ out) {
  if (threadIdx.x != 0 || blockIdx.x != 0) return;
  float al = anchor_acc[0] / fmaxf(anchor_acc[1], 1.0f);
  float pl = proto_acc[0] / fmaxf(proto_acc[1], 1.0f);
  out[0] = pl + 1.0f * al + 0.1f * compact[0];
}

// ---------------- host ----------------

static void host_keys(RKeys* K) {
  const u32 b0 = 0u, b1 = 42u;
  u32 o0, o1;
  for (int i = 0; i < LBN; ++i) {
    u32 f0, f1;
    tf2x32(b0, b1, 0u, (u32)i, &f0, &f1);
    u32 p0, q0, p1, q1;
    tf2x32(f0, f1, 0u, 2u, &p0, &q0);
    tf2x32(f0, f1, 1u, 3u, &p1, &q1);
    K->ki[i][0] = p0; K->ki[i][1] = p1;
    K->kf[i][0] = q0; K->kf[i][1] = q1;
  }
  tf2x32(b0, b1, 0u, 1000u, &o0, &o1); K->k1000[0] = o0; K->k1000[1] = o1;
  tf2x32(b0, b1, 0u, 2000u, &o0, &o1); K->k2000[0] = o0; K->k2000[1] = o1;
  tf2x32(b0, b1, 0u, 2001u, &o0, &o1); K->k2001[0] = o0; K->k2001[1] = o1;
}

extern "C" void kernel_launch(void* const* d_in, const int* in_sizes, int n_in,
                              void* d_out, int out_size, void* d_ws, size_t ws_size,
                              hipStream_t stream) {
  const float* feats = (const float*)d_in[0];
  const float* protos = (const float*)d_in[1];
  const int* pseudo = (const int*)d_in[2];
  const int* gt = (const int*)d_in[3];
  const int* labeled = (const int*)d_in[4];
  float* out = (float*)d_out;

  int N = in_sizes[2];
  int Z3 = N / 4;

  RKeys RK;
  host_keys(&RK);

  char* W = (char*)d_ws;
  size_t off = 0;
  auto alloc = [&](size_t bytes) -> char* {
    char* p = W + off;
    off += (bytes + 255) & ~(size_t)255;
    return p;
  };
  char* stateBase = W + off;
  u64* top5A = (u64*)alloc((size_t)6 * LBN * NBLKA * 5 * 8);
  u64* top5F = (u64*)alloc((size_t)6 * LBN * 5 * 8);
  float* cent = (float*)alloc((size_t)LBN * KMX * DD * 4);
  float* sums = (float*)alloc((size_t)(LBN * KMX * DD + LBN * KMX) * 4);
  float* kcnt = sums + LBN * KMX * DD;
  float* protn = (float*)alloc((size_t)CKK * DD * 4);
  float* compact = (float*)alloc(256);
  float* anchor_acc = (float*)alloc(256);
  float* proto_acc = (float*)alloc(256);
  u32* hist = (u32*)alloc(2048 * 4);
  SelState* st = (SelState*)alloc(256);
  u64* cand = (u64*)alloc(4096 * 8);
  int* aidx = (int*)alloc((size_t)MAXA * 4);
  int* alab = (int*)alloc((size_t)MAXA * 4);
  float* afe = (float*)alloc((size_t)MAXA * DD * 4);
  if (ws_size < off) return;

  size_t stateBytes = (size_t)((W + off) - stateBase);
  hipMemsetAsync(stateBase, 0, stateBytes, stream);

  k_protos<<<dim3(1), dim3(256), 0, stream>>>(protos, protn, compact);

  k_top5A<<<dim3(NBLKA, 6), dim3(256), 0, stream>>>(gt, labeled, RK, top5A, N);
  k_top5B<<<dim3(6, LBN), dim3(256), 0, stream>>>(top5A, top5F, NBLKA);

  k_initcent<<<dim3(1), dim3(LBN * KMX * DD), 0, stream>>>(feats, top5F, cent, N, Z3);
  int nbAssign = (N + 511) / 512;
  for (int it = 0; it < KIT; ++it) {
    hipMemsetAsync(sums, 0, (size_t)(LBN * KMX * DD + LBN * KMX) * 4, stream);
    k_assign<<<dim3(nbAssign), dim3(256), 0, stream>>>(feats, gt, labeled, cent, sums, kcnt, N, Z3);
    k_update<<<dim3(1), dim3(LBN * KMX * DD), 0, stream>>>(feats, top5F, sums, kcnt, cent, it, N, Z3);
  }
  k_anchor_final<<<dim3(LBN), dim3(64), 0, stream>>>(cent, sums, kcnt, protn, labeled, anchor_acc);

  k_hist<<<dim3(1024), dim3(256), 0, stream>>>(pseudo, RK, hist, st, 0, N);
  k_scan<<<dim3(1), dim3(256), 0, stream>>>(hist, st, 0);
  hipMemsetAsync(hist, 0, 2048 * 4, stream);
  k_hist<<<dim3(1024), dim3(256), 0, stream>>>(pseudo, RK, hist, st, 1, N);
  k_scan<<<dim3(1), dim3(256), 0, stream>>>(hist, st, 1);
  hipMemsetAsync(hist, 0, 2048 * 4, stream);
  k_hist<<<dim3(1024), dim3(256), 0, stream>>>(pseudo, RK, hist, st, 2, N);
  k_scan<<<dim3(1), dim3(256), 0, stream>>>(hist, st, 2);
  k_gather<<<dim3(1024), dim3(256), 0, stream>>>(pseudo, RK, st, cand, N);
  k_sortsel<<<dim3(1), dim3(1024), 0, stream>>>(cand, st, aidx);

  k_prep<<<dim3(MAXA / 256), dim3(256), 0, stream>>>(feats, pseudo, st, aidx, afe, alab, N, Z3);
  k_triplet<<<dim3(MAXA / 256), dim3(256), 0, stream>>>(protn, afe, alab, st, RK, proto_acc);

  k_final<<<dim3(1), dim3(64), 0, stream>>>(anchor_acc, proto_acc, compact, out);
}